// Round 18
// baseline (111.934 us; speedup 1.0000x reference)
//
#include <hip/hip_runtime.h>
#include <hip/hip_bf16.h>
#include <stdint.h>

typedef unsigned short u16;
typedef __attribute__((ext_vector_type(8))) short short8;
typedef __attribute__((ext_vector_type(4))) float f32x4;

// ws layout (bytes): [0,8M) x_bf16 [8M,16M) Wt(4x1Mx2B) [16M,24M) q
// [24M,32M) k [32M,40M) v^T [B,H,D,T] [40M,48M) y
static __device__ __forceinline__ u16 f2bf(float f) {
  unsigned u = __builtin_bit_cast(unsigned, f);
  u += 0x7fffu + ((u >> 16) & 1u);
  return (u16)(u >> 16);
}

static __device__ __forceinline__ unsigned cvtpk(float lo, float hi) {
  unsigned r;
  asm("v_cvt_pk_bf16_f32 %0, %1, %2" : "=v"(r) : "v"(lo), "v"(hi));
  return r;
}

static __device__ __forceinline__ void gload16(const u16* g, u16* l) {
  __builtin_amdgcn_global_load_lds(
      (__attribute__((address_space(1))) void*)const_cast<u16*>(g),
      (__attribute__((address_space(3))) void*)l, 16, 0, 0);
}

// ---------------- fused prep: x fp32->bf16 (blocks 0..2047) +
//                  W [k][n] fp32 -> Wt [n][k] bf16 (blocks 2048..3071) ----------
__global__ __launch_bounds__(256) void prep_kernel(
    const float* __restrict__ x, const float* __restrict__ Wq,
    const float* __restrict__ Wk, const float* __restrict__ Wv,
    const float* __restrict__ Wp, u16* __restrict__ xb, u16* __restrict__ wt) {
  __shared__ float tile[64][65];
  int b = blockIdx.x;
  if (b < 2048) {
    size_t i = (size_t)b * 256 + threadIdx.x;  // 8 floats per thread
    const float4* xp = (const float4*)x + i * 2;
    float4 a = xp[0], v = xp[1];
    union { u16 u[8]; int4 q; } r;
    r.u[0] = f2bf(a.x); r.u[1] = f2bf(a.y); r.u[2] = f2bf(a.z); r.u[3] = f2bf(a.w);
    r.u[4] = f2bf(v.x); r.u[5] = f2bf(v.y); r.u[6] = f2bf(v.z); r.u[7] = f2bf(v.w);
    *(int4*)(xb + i * 8) = r.q;
  } else {
    int wb = b - 2048;
    int wz = wb >> 8, r8 = wb & 255;
    const float* W = (wz == 0) ? Wq : (wz == 1) ? Wk : (wz == 2) ? Wv : Wp;
    int n0 = (r8 & 15) * 64, k0 = (r8 >> 4) * 64;
    int tx = threadIdx.x & 63, ty = threadIdx.x >> 6;
#pragma unroll
    for (int r = 0; r < 16; ++r)
      tile[ty + 4 * r][tx] = W[(size_t)(k0 + ty + 4 * r) * 1024 + n0 + tx];
    __syncthreads();
    u16* dst = wt + (size_t)wz * 1024 * 1024;
#pragma unroll
    for (int r = 0; r < 16; ++r) {
      int n = ty + 4 * r;
      dst[(size_t)(n0 + n) * 1024 + k0 + tx] = f2bf(tile[tx][n]);
    }
  }
}

// ---------------- QKV 128x128 MFMA GEMM, BK=64, single-buffered ----------------
// Q output is pre-scaled by 0.125*log2(e) so fattn's exp2 consumes raw MFMA S.
__global__ __launch_bounds__(256, 2) void gemm_qkv_kernel(
    const u16* __restrict__ A, const u16* __restrict__ Bt, int Kdim,
    int GM, int GN, int RM, int RN,
    u16* __restrict__ qd, u16* __restrict__ kd, u16* __restrict__ vd,
    const float* __restrict__ bq, const float* __restrict__ bk,
    const float* __restrict__ bv) {
  __shared__ u16 Alds[8192];
  __shared__ u16 Blds[8192];
  int tid = threadIdx.x;
  int lane = tid & 63, w = tid >> 6;
  int l15 = lane & 15, lg = lane >> 4;
  int flat = blockIdx.x;
  int xcd = flat & 7, idx = flat >> 3;
  int rnc = GN / RN;
  int rm = (xcd / rnc) * RM, rn = (xcd % rnc) * RN;
  int im = idx % RM, in_ = idx / RM;
  int m0 = (rm + im) * 128, n0 = (rn + in_) * 128;
  int wm = (w >> 1) * 64, wn = (w & 1) * 64;
  int srow = lane >> 3;
  int colsw = ((lane & 7) * 8) ^ ((srow & 7) * 8);  // pre-swizzled source col
  const float SC = 0.125f * 1.44269504088896340736f;

  const u16* pA[4];
  const u16* pB[4];
  int dls[4];
#pragma unroll
  for (int j = 0; j < 4; ++j) {
    int issue = w * 4 + j;
    int row = issue * 8 + srow;
    pA[j] = A + (size_t)(m0 + row) * Kdim + colsw;
    pB[j] = Bt + (size_t)(n0 + row) * Kdim + colsw;
    dls[j] = issue * 512;
  }
  int kx = (l15 & 7) << 4;
  int ofs0 = (lg * 16) ^ kx, ofs1 = (64 + lg * 16) ^ kx;
  int rbA = (wm + l15) * 128, rbB = (wn + l15) * 128;

  f32x4 acc[4][4] = {};
  for (int kt = 0; kt < Kdim; kt += 64) {
#pragma unroll
    for (int j = 0; j < 4; ++j) {
      gload16(pA[j], Alds + dls[j]);
      gload16(pB[j], Blds + dls[j]);
      pA[j] += 64; pB[j] += 64;
    }
    __syncthreads();  // drain vmcnt -> buf ready
    __builtin_amdgcn_s_setprio(1);
#pragma unroll
    for (int kk = 0; kk < 2; ++kk) {
      int o_ = kk ? ofs1 : ofs0;
      short8 a[4], b[4];
#pragma unroll
      for (int mt = 0; mt < 4; ++mt)
        a[mt] = *(const short8*)((const char*)Alds + (rbA + o_) + mt * 2048);
#pragma unroll
      for (int nt = 0; nt < 4; ++nt)
        b[nt] = *(const short8*)((const char*)Blds + (rbB + o_) + nt * 2048);
#pragma unroll
      for (int mt = 0; mt < 4; ++mt)
#pragma unroll
        for (int nt = 0; nt < 4; ++nt)
          acc[mt][nt] = __builtin_amdgcn_mfma_f32_16x16x32_bf16(a[mt], b[nt],
                                                                acc[mt][nt], 0, 0, 0);
    }
    __builtin_amdgcn_s_setprio(0);
    __syncthreads();  // all waves done reading before next stage
  }
#pragma unroll
  for (int nt = 0; nt < 4; ++nt) {
    int n = n0 + wn + nt * 16 + l15;
    int wi = n >> 10, nn = n & 1023, h = nn >> 6, d = nn & 63;
    const float* bb = (wi == 0) ? bq : (wi == 1) ? bk : bv;
    float bval = bb[nn];
    if (wi == 2) {  // V: write transposed [B,H,D,T], 4 consecutive t -> uint2
#pragma unroll
      for (int mt = 0; mt < 4; ++mt) {
        int m = m0 + wm + mt * 16 + lg * 4;
        int mb = m >> 11, t = m & 2047;
        unsigned lo = cvtpk(acc[mt][nt][0] + bval, acc[mt][nt][1] + bval);
        unsigned hi = cvtpk(acc[mt][nt][2] + bval, acc[mt][nt][3] + bval);
        *(uint2*)&vd[((size_t)(mb * 16 + h) * 64 + d) * 2048 + t] =
            make_uint2(lo, hi);
      }
    } else if (wi == 0) {  // Q: pre-scaled by SC (softmax shift-invariance)
#pragma unroll
      for (int mt = 0; mt < 4; ++mt) {
#pragma unroll
        for (int i = 0; i < 4; ++i) {
          int m = m0 + wm + mt * 16 + lg * 4 + i;
          int mb = m >> 11, t = m & 2047;
          qd[((size_t)(mb * 16 + h) * 2048 + t) * 64 + d] =
              f2bf((acc[mt][nt][i] + bval) * SC);
        }
      }
    } else {
#pragma unroll
      for (int mt = 0; mt < 4; ++mt) {
#pragma unroll
        for (int i = 0; i < 4; ++i) {
          int m = m0 + wm + mt * 16 + lg * 4 + i;
          int mb = m >> 11, t = m & 2047;
          kd[((size_t)(mb * 16 + h) * 2048 + t) * 64 + d] =
              f2bf(acc[mt][nt][i] + bval);
        }
      }
    }
  }
}

// ---------------- proj 128x64 MFMA GEMM, BK=64, double-buffered ----------------
__global__ __launch_bounds__(256, 2) void gemm_proj_kernel(
    const u16* __restrict__ A, const u16* __restrict__ Bt,
    float* __restrict__ outf, const float* __restrict__ bias1) {
  __shared__ u16 Alds[2 * 8192];   // [2][128][64]
  __shared__ u16 Blds[2 * 4096];   // [2][64][64]
  int tid = threadIdx.x;
  int lane = tid & 63, w = tid >> 6;
  int l15 = lane & 15, lg = lane >> 4;
  int flat = blockIdx.x;
  int xcd = flat & 7, idx = flat >> 3;           // idx 0..63
  int rm = (xcd >> 1) * 8, rn = (xcd & 1) * 8;   // region: 8 mtiles x 8 ntiles
  int m0 = (rm + (idx & 7)) * 128, n0 = (rn + (idx >> 3)) * 64;
  int wm = (w >> 1) * 64, wn = (w & 1) * 32;
  int srow = lane >> 3;
  int colsw = ((lane & 7) * 8) ^ ((srow & 7) * 8);  // pre-swizzled source col

  const u16* pA[4];
  int dlsA[4];
#pragma unroll
  for (int j = 0; j < 4; ++j) {
    int issue = w * 4 + j;
    int row = issue * 8 + srow;
    pA[j] = A + (size_t)(m0 + row) * 1024 + colsw;
    dlsA[j] = issue * 512;
  }
  const u16* pB[2];
  int dlsB[2];
#pragma unroll
  for (int it = 0; it < 2; ++it) {
    int chunk = it * 256 + tid;
    int row = chunk >> 3;
    int col = ((chunk & 7) * 8) ^ ((row & 7) * 8);
    pB[it] = Bt + (size_t)(n0 + row) * 1024 + col;
    dlsB[it] = (it * 256 + w * 64) * 8;
  }
  int kx = (l15 & 7) << 4;
  int ofs0 = (lg * 16) ^ kx, ofs1 = (64 + lg * 16) ^ kx;
  int rbA = (wm + l15) * 128, rbB = (wn + l15) * 128;

  auto stage = [&](int buf) {
    u16* Ad = Alds + buf * 8192;
    u16* Bd = Blds + buf * 4096;
#pragma unroll
    for (int j = 0; j < 4; ++j) { gload16(pA[j], Ad + dlsA[j]); pA[j] += 64; }
#pragma unroll
    for (int it = 0; it < 2; ++it) { gload16(pB[it], Bd + dlsB[it]); pB[it] += 64; }
  };

  f32x4 acc[4][2] = {};
  stage(0);
  int cur = 0;
  for (int kt = 0; kt < 1024; kt += 64) {
    __syncthreads();  // drain vmcnt -> buf[cur] ready
    if (kt + 64 < 1024) stage(cur ^ 1);
    const char* Al = (const char*)Alds + cur * 16384;
    const char* Bl = (const char*)Blds + cur * 8192;
    __builtin_amdgcn_s_setprio(1);
#pragma unroll
    for (int kk = 0; kk < 2; ++kk) {
      int o_ = kk ? ofs1 : ofs0;
      short8 a[4], b[2];
#pragma unroll
      for (int mt = 0; mt < 4; ++mt)
        a[mt] = *(const short8*)(Al + (rbA + o_) + mt * 2048);
#pragma unroll
      for (int nt = 0; nt < 2; ++nt)
        b[nt] = *(const short8*)(Bl + (rbB + o_) + nt * 2048);
#pragma unroll
      for (int mt = 0; mt < 4; ++mt)
#pragma unroll
        for (int nt = 0; nt < 2; ++nt)
          acc[mt][nt] = __builtin_amdgcn_mfma_f32_16x16x32_bf16(a[mt], b[nt],
                                                                acc[mt][nt], 0, 0, 0);
    }
    __builtin_amdgcn_s_setprio(0);
    cur ^= 1;
  }
#pragma unroll
  for (int nt = 0; nt < 2; ++nt) {
    int n = n0 + wn + nt * 16 + l15;
    float bval = bias1[n];
#pragma unroll
    for (int mt = 0; mt < 4; ++mt) {
#pragma unroll
      for (int i = 0; i < 4; ++i) {
        int m = m0 + wm + mt * 16 + lg * 4 + i;
        outf[(size_t)m * 1024 + n] = acc[mt][nt][i] + bval;
      }
    }
  }
}

// ---------------- causal flash attention, QBLK=128, 2 q-subtiles per wave -----
// R17's shift-free structure, but each wave owns TWO 16-row q-subtiles
// (rows qt*128+w*16 and +64). The ka/bv LDS fragments depend only on the lane,
// so ONE set of K/V reads feeds BOTH subtiles' MFMAs -> LDS read traffic per
// q-row nearly halves (fattn was LDS-BW-bound: ~6.3MB/CU @ ~85B/cyc).
// Grid 512 = 2 blocks/CU, complementary pairing (per-CU tile sum = 34).
// Sub0 skips the final fully-masked tile via a block-uniform guard.
__global__ __launch_bounds__(256, 2) void fattn_kernel(const u16* __restrict__ qb,
                                                       const u16* __restrict__ kb,
                                                       const u16* __restrict__ vt,
                                                       u16* __restrict__ y) {
  __shared__ u16 Klds[4096];
  __shared__ u16 Vlds[4096];   // V^T: [d][kv], swizzled
  __shared__ u16 Plds[4096];   // 4 waves x 2KB, reused sub0 then sub1
  int tid = threadIdx.x, lane = tid & 63, w = tid >> 6;
  int l15 = lane & 15, lg = lane >> 4;
  int flat = blockIdx.x;
  int bh = flat & 31;
  int s_ = flat >> 5;                 // 0..15
  int qt = (s_ < 8) ? (15 - s_) : (s_ - 8);  // long round then short round
  size_t base = (size_t)bh * 2048 * 64;
  int mb = bh >> 4, h = bh & 15;

  // ---- hoisted staging geometry (advance per tile: K +4096, V +64 elem) ----
  int r0 = tid >> 3, c0 = ((tid & 7) * 8) ^ ((r0 & 7) << 3);
  int r1 = (256 + tid) >> 3, c1 = ((tid & 7) * 8) ^ ((r1 & 7) << 3);
  const u16* pK0 = kb + base + (size_t)r0 * 64 + c0;
  const u16* pK1 = kb + base + (size_t)r1 * 64 + c1;
  const u16* pV0 = vt + base + (size_t)r0 * 2048 + c0;
  const u16* pV1 = vt + base + (size_t)r1 * 2048 + c1;
  int dk0 = w * 512, dk1 = (256 + w * 64) * 8;   // LDS dest offsets (u16)
  // ---- hoisted LDS read bases (bytes); shared by K, V, P reads ----
  int kx = (l15 & 7) << 4;
  int rb0 = l15 * 128 + ((lg * 16) ^ kx);
  int rb1 = l15 * 128 + ((64 + lg * 16) ^ kx);
  char* pbase = (char*)Plds + w * 2048;
  int pw0 = l15 * 128 + ((lg * 8) ^ kx);
  int pw1 = l15 * 128 + ((32 + lg * 8) ^ kx);
  int pw2 = l15 * 128 + ((64 + lg * 8) ^ kx);
  int pw3 = l15 * 128 + ((96 + lg * 8) ^ kx);

  int qr0 = qt * 128 + w * 16 + l15;
  int qr1 = qr0 + 64;
  short8 qf[2][2];
#pragma unroll
  for (int sub = 0; sub < 2; ++sub)
#pragma unroll
    for (int kk = 0; kk < 2; ++kk)
      qf[sub][kk] = *(const short8*)&qb[base + (size_t)(qr0 + sub * 64) * 64 +
                                        kk * 32 + lg * 8];
  f32x4 o0[4] = {}, o1[4] = {};
  float lr0 = 0.f, lr1 = 0.f;
  int ntiles = 2 * qt + 2;
  for (int j = 0; j < ntiles; ++j) {
    // stage tile j into the single buffer
    gload16(pK0, Klds + dk0); gload16(pK1, Klds + dk1);
    gload16(pV0, Vlds + dk0); gload16(pV1, Vlds + dk1);
    pK0 += 4096; pK1 += 4096; pV0 += 64; pV1 += 64;
    __syncthreads();  // compiler drains vmcnt before barrier: buf ready
    bool do0 = (j + 1 < ntiles);  // sub0 skips its fully-masked last tile
    // read ka ONCE; feeds both subtiles
    short8 ka[2][4];
#pragma unroll
    for (int kk = 0; kk < 2; ++kk) {
      int o_ = kk ? rb1 : rb0;
#pragma unroll
      for (int nt = 0; nt < 4; ++nt)
        ka[kk][nt] = *(const short8*)((const char*)Klds + o_ + nt * 2048);
    }
    f32x4 s0[4] = {}, s1[4] = {};
    __builtin_amdgcn_s_setprio(1);
    if (do0) {
#pragma unroll
      for (int kk = 0; kk < 2; ++kk)
#pragma unroll
        for (int nt = 0; nt < 4; ++nt)
          s0[nt] = __builtin_amdgcn_mfma_f32_16x16x32_bf16(ka[kk][nt], qf[0][kk],
                                                           s0[nt], 0, 0, 0);
    }
#pragma unroll
    for (int kk = 0; kk < 2; ++kk)
#pragma unroll
      for (int nt = 0; nt < 4; ++nt)
        s1[nt] = __builtin_amdgcn_mfma_f32_16x16x32_bf16(ka[kk][nt], qf[1][kk],
                                                         s1[nt], 0, 0, 0);
    __builtin_amdgcn_s_setprio(0);
    // read bv ONCE; feeds both subtiles' PV
    short8 bv[2][4];
#pragma unroll
    for (int kk = 0; kk < 2; ++kk) {
      int o_ = kk ? rb1 : rb0;
#pragma unroll
      for (int nt = 0; nt < 4; ++nt)
        bv[kk][nt] = *(const short8*)((const char*)Vlds + o_ + nt * 2048);
    }
    int k0 = j * 64;
    // ---- sub0: softmax + PV (guarded, block-uniform, no barriers inside) ----
    if (do0) {
      float p[16];
      if (j == ntiles - 2) {  // sub0 diagonal
#pragma unroll
        for (int nt = 0; nt < 4; ++nt)
#pragma unroll
          for (int i = 0; i < 4; ++i) {
            int ka_ = k0 + nt * 16 + lg * 4 + i;
            p[nt * 4 + i] = (ka_ > qr0) ? 0.f : exp2f(s0[nt][i]);
          }
      } else {
#pragma unroll
        for (int nt = 0; nt < 4; ++nt)
#pragma unroll
          for (int i = 0; i < 4; ++i) p[nt * 4 + i] = exp2f(s0[nt][i]);
      }
      lr0 += (((p[0] + p[1]) + (p[2] + p[3])) + ((p[4] + p[5]) + (p[6] + p[7]))) +
             (((p[8] + p[9]) + (p[10] + p[11])) + ((p[12] + p[13]) + (p[14] + p[15])));
      *(uint2*)(pbase + pw0) = make_uint2(cvtpk(p[0], p[1]), cvtpk(p[2], p[3]));
      *(uint2*)(pbase + pw1) = make_uint2(cvtpk(p[4], p[5]), cvtpk(p[6], p[7]));
      *(uint2*)(pbase + pw2) = make_uint2(cvtpk(p[8], p[9]), cvtpk(p[10], p[11]));
      *(uint2*)(pbase + pw3) = make_uint2(cvtpk(p[12], p[13]), cvtpk(p[14], p[15]));
      __builtin_amdgcn_s_setprio(1);
#pragma unroll
      for (int kk = 0; kk < 2; ++kk) {
        short8 ap = *(const short8*)(pbase + (kk ? rb1 : rb0));
#pragma unroll
        for (int dn = 0; dn < 4; ++dn)
          o0[dn] = __builtin_amdgcn_mfma_f32_16x16x32_bf16(bv[kk][dn], ap,
                                                           o0[dn], 0, 0, 0);
      }
      __builtin_amdgcn_s_setprio(0);
    }
    // ---- sub1: softmax + PV (P buffer reused; wave-local ordering) ----
    {
      float p[16];
      if (j == ntiles - 1) {  // sub1 diagonal
#pragma unroll
        for (int nt = 0; nt < 4; ++nt)
#pragma unroll
          for (int i = 0; i < 4; ++i) {
            int ka_ = k0 + nt * 16 + lg * 4 + i;
            p[nt * 4 + i] = (ka_ > qr1) ? 0.f : exp2f(s1[nt][i]);
          }
      } else {
#pragma unroll
        for (int nt = 0; nt < 4; ++nt)
#pragma unroll
          for (int i = 0; i < 4; ++i) p[nt * 4 + i] = exp2f(s1[nt][i]);
      }
      lr1 += (((p[0] + p[1]) + (p[2] + p[3])) + ((p[4] + p[5]) + (p[6] + p[7]))) +
             (((p[8] + p[9]) + (p[10] + p[11])) + ((p[12] + p[13]) + (p[14] + p[15])));
      *(uint2*)(pbase + pw0) = make_uint2(cvtpk(p[0], p[1]), cvtpk(p[2], p[3]));
      *(uint2*)(pbase + pw1) = make_uint2(cvtpk(p[4], p[5]), cvtpk(p[6], p[7]));
      *(uint2*)(pbase + pw2) = make_uint2(cvtpk(p[8], p[9]), cvtpk(p[10], p[11]));
      *(uint2*)(pbase + pw3) = make_uint2(cvtpk(p[12], p[13]), cvtpk(p[14], p[15]));
      __builtin_amdgcn_s_setprio(1);
#pragma unroll
      for (int kk = 0; kk < 2; ++kk) {
        short8 ap = *(const short8*)(pbase + (kk ? rb1 : rb0));
#pragma unroll
        for (int dn = 0; dn < 4; ++dn)
          o1[dn] = __builtin_amdgcn_mfma_f32_16x16x32_bf16(bv[kk][dn], ap,
                                                           o1[dn], 0, 0, 0);
      }
      __builtin_amdgcn_s_setprio(0);
    }
    __syncthreads();  // all waves done reading K/V before next stage
  }
  // combine partials across the 4 lane-groups of each q-row; write both subs
  lr0 += __shfl_xor(lr0, 16);
  lr0 += __shfl_xor(lr0, 32);
  lr1 += __shfl_xor(lr1, 16);
  lr1 += __shfl_xor(lr1, 32);
  float inv0 = 1.f / lr0, inv1 = 1.f / lr1;
  size_t rb_0 = ((size_t)(mb * 2048 + qr0)) * 1024 + (size_t)h * 64;
  size_t rb_1 = ((size_t)(mb * 2048 + qr1)) * 1024 + (size_t)h * 64;
#pragma unroll
  for (int dn = 0; dn < 4; ++dn) {
    unsigned lo = cvtpk(o0[dn][0] * inv0, o0[dn][1] * inv0);
    unsigned hi = cvtpk(o0[dn][2] * inv0, o0[dn][3] * inv0);
    *(uint2*)&y[rb_0 + dn * 16 + lg * 4] = make_uint2(lo, hi);
  }
#pragma unroll
  for (int dn = 0; dn < 4; ++dn) {
    unsigned lo = cvtpk(o1[dn][0] * inv1, o1[dn][1] * inv1);
    unsigned hi = cvtpk(o1[dn][2] * inv1, o1[dn][3] * inv1);
    *(uint2*)&y[rb_1 + dn * 16 + lg * 4] = make_uint2(lo, hi);
  }
}

extern "C" void kernel_launch(void* const* d_in, const int* in_sizes, int n_in,
                              void* d_out, int out_size, void* d_ws, size_t ws_size,
                              hipStream_t stream) {
  const float* x  = (const float*)d_in[0];
  const float* Wq = (const float*)d_in[1];
  const float* bq = (const float*)d_in[2];
  const float* Wk = (const float*)d_in[3];
  const float* bk = (const float*)d_in[4];
  const float* Wv = (const float*)d_in[5];
  const float* bv = (const float*)d_in[6];
  const float* Wp = (const float*)d_in[7];
  const float* bp = (const float*)d_in[8];
  float* out = (float*)d_out;
  char* ws = (char*)d_ws;
  u16* xb   = (u16*)(ws);
  u16* wt   = (u16*)(ws + ((size_t)8 << 20));
  u16* qbuf = (u16*)(ws + ((size_t)16 << 20));
  u16* kbuf = (u16*)(ws + ((size_t)24 << 20));
  u16* vtb  = (u16*)(ws + ((size_t)32 << 20));  // V^T written by QKV epilogue
  u16* ybuf = (u16*)(ws + ((size_t)40 << 20));

  prep_kernel<<<dim3(3072), dim3(256), 0, stream>>>(x, Wq, Wk, Wv, Wp, xb, wt);
  // QKV: M=4096 (GM=32), N=3072 (GN=24); per-XCD region 8x12; single-buffered
  gemm_qkv_kernel<<<dim3(768), dim3(256), 0, stream>>>(
      xb, wt, 1024, 32, 24, 8, 12, qbuf, kbuf, vtb, bq, bk, bv);
  fattn_kernel<<<dim3(512), dim3(256), 0, stream>>>(qbuf, kbuf, vtb, ybuf);
  // proj: 128x64 tiles, grid 512 (2 blocks/CU co-resident), double-buffered
  gemm_proj_kernel<<<dim3(512), dim3(256), 0, stream>>>(
      ybuf, wt + (size_t)3 * 1024 * 1024, out, bp);
  (void)in_sizes; (void)n_in; (void)out_size; (void)ws_size;
}

// Round 19
// 97.656 us; speedup vs baseline: 1.1462x; 1.1462x over previous
//
#include <hip/hip_runtime.h>
#include <hip/hip_bf16.h>
#include <stdint.h>

typedef unsigned short u16;
typedef __attribute__((ext_vector_type(8))) short short8;
typedef __attribute__((ext_vector_type(4))) float f32x4;

// ws layout (bytes): [0,8M) x_bf16 [8M,16M) Wt(4x1Mx2B) [16M,24M) q
// [24M,32M) k [32M,40M) v^T [B,H,D,T] [40M,48M) y
static __device__ __forceinline__ u16 f2bf(float f) {
  unsigned u = __builtin_bit_cast(unsigned, f);
  u += 0x7fffu + ((u >> 16) & 1u);
  return (u16)(u >> 16);
}

static __device__ __forceinline__ unsigned cvtpk(float lo, float hi) {
  unsigned r;
  asm("v_cvt_pk_bf16_f32 %0, %1, %2" : "=v"(r) : "v"(lo), "v"(hi));
  return r;
}

static __device__ __forceinline__ void gload16(const u16* g, u16* l) {
  __builtin_amdgcn_global_load_lds(
      (__attribute__((address_space(1))) void*)const_cast<u16*>(g),
      (__attribute__((address_space(3))) void*)l, 16, 0, 0);
}

// ---------------- fused prep: x fp32->bf16 (blocks 0..2047) +
//                  W [k][n] fp32 -> Wt [n][k] bf16 (blocks 2048..3071) ----------
__global__ __launch_bounds__(256) void prep_kernel(
    const float* __restrict__ x, const float* __restrict__ Wq,
    const float* __restrict__ Wk, const float* __restrict__ Wv,
    const float* __restrict__ Wp, u16* __restrict__ xb, u16* __restrict__ wt) {
  __shared__ float tile[64][65];
  int b = blockIdx.x;
  if (b < 2048) {
    size_t i = (size_t)b * 256 + threadIdx.x;  // 8 floats per thread
    const float4* xp = (const float4*)x + i * 2;
    float4 a = xp[0], v = xp[1];
    union { u16 u[8]; int4 q; } r;
    r.u[0] = f2bf(a.x); r.u[1] = f2bf(a.y); r.u[2] = f2bf(a.z); r.u[3] = f2bf(a.w);
    r.u[4] = f2bf(v.x); r.u[5] = f2bf(v.y); r.u[6] = f2bf(v.z); r.u[7] = f2bf(v.w);
    *(int4*)(xb + i * 8) = r.q;
  } else {
    int wb = b - 2048;
    int wz = wb >> 8, r8 = wb & 255;
    const float* W = (wz == 0) ? Wq : (wz == 1) ? Wk : (wz == 2) ? Wv : Wp;
    int n0 = (r8 & 15) * 64, k0 = (r8 >> 4) * 64;
    int tx = threadIdx.x & 63, ty = threadIdx.x >> 6;
#pragma unroll
    for (int r = 0; r < 16; ++r)
      tile[ty + 4 * r][tx] = W[(size_t)(k0 + ty + 4 * r) * 1024 + n0 + tx];
    __syncthreads();
    u16* dst = wt + (size_t)wz * 1024 * 1024;
#pragma unroll
    for (int r = 0; r < 16; ++r) {
      int n = ty + 4 * r;
      dst[(size_t)(n0 + n) * 1024 + k0 + tx] = f2bf(tile[tx][n]);
    }
  }
}

// ---------------- QKV 128x128 MFMA GEMM, BK=64, single-buffered ----------------
// Q output is pre-scaled by 0.125*log2(e) so fattn's exp2 consumes raw MFMA S.
__global__ __launch_bounds__(256, 2) void gemm_qkv_kernel(
    const u16* __restrict__ A, const u16* __restrict__ Bt, int Kdim,
    int GM, int GN, int RM, int RN,
    u16* __restrict__ qd, u16* __restrict__ kd, u16* __restrict__ vd,
    const float* __restrict__ bq, const float* __restrict__ bk,
    const float* __restrict__ bv) {
  __shared__ u16 Alds[8192];
  __shared__ u16 Blds[8192];
  int tid = threadIdx.x;
  int lane = tid & 63, w = tid >> 6;
  int l15 = lane & 15, lg = lane >> 4;
  int flat = blockIdx.x;
  int xcd = flat & 7, idx = flat >> 3;
  int rnc = GN / RN;
  int rm = (xcd / rnc) * RM, rn = (xcd % rnc) * RN;
  int im = idx % RM, in_ = idx / RM;
  int m0 = (rm + im) * 128, n0 = (rn + in_) * 128;
  int wm = (w >> 1) * 64, wn = (w & 1) * 64;
  int srow = lane >> 3;
  int colsw = ((lane & 7) * 8) ^ ((srow & 7) * 8);  // pre-swizzled source col
  const float SC = 0.125f * 1.44269504088896340736f;

  const u16* pA[4];
  const u16* pB[4];
  int dls[4];
#pragma unroll
  for (int j = 0; j < 4; ++j) {
    int issue = w * 4 + j;
    int row = issue * 8 + srow;
    pA[j] = A + (size_t)(m0 + row) * Kdim + colsw;
    pB[j] = Bt + (size_t)(n0 + row) * Kdim + colsw;
    dls[j] = issue * 512;
  }
  int kx = (l15 & 7) << 4;
  int ofs0 = (lg * 16) ^ kx, ofs1 = (64 + lg * 16) ^ kx;
  int rbA = (wm + l15) * 128, rbB = (wn + l15) * 128;

  f32x4 acc[4][4] = {};
  for (int kt = 0; kt < Kdim; kt += 64) {
#pragma unroll
    for (int j = 0; j < 4; ++j) {
      gload16(pA[j], Alds + dls[j]);
      gload16(pB[j], Blds + dls[j]);
      pA[j] += 64; pB[j] += 64;
    }
    __syncthreads();  // drain vmcnt -> buf ready
    __builtin_amdgcn_s_setprio(1);
#pragma unroll
    for (int kk = 0; kk < 2; ++kk) {
      int o_ = kk ? ofs1 : ofs0;
      short8 a[4], b[4];
#pragma unroll
      for (int mt = 0; mt < 4; ++mt)
        a[mt] = *(const short8*)((const char*)Alds + (rbA + o_) + mt * 2048);
#pragma unroll
      for (int nt = 0; nt < 4; ++nt)
        b[nt] = *(const short8*)((const char*)Blds + (rbB + o_) + nt * 2048);
#pragma unroll
      for (int mt = 0; mt < 4; ++mt)
#pragma unroll
        for (int nt = 0; nt < 4; ++nt)
          acc[mt][nt] = __builtin_amdgcn_mfma_f32_16x16x32_bf16(a[mt], b[nt],
                                                                acc[mt][nt], 0, 0, 0);
    }
    __builtin_amdgcn_s_setprio(0);
    __syncthreads();  // all waves done reading before next stage
  }
#pragma unroll
  for (int nt = 0; nt < 4; ++nt) {
    int n = n0 + wn + nt * 16 + l15;
    int wi = n >> 10, nn = n & 1023, h = nn >> 6, d = nn & 63;
    const float* bb = (wi == 0) ? bq : (wi == 1) ? bk : bv;
    float bval = bb[nn];
    if (wi == 2) {  // V: write transposed [B,H,D,T], 4 consecutive t -> uint2
#pragma unroll
      for (int mt = 0; mt < 4; ++mt) {
        int m = m0 + wm + mt * 16 + lg * 4;
        int mb = m >> 11, t = m & 2047;
        unsigned lo = cvtpk(acc[mt][nt][0] + bval, acc[mt][nt][1] + bval);
        unsigned hi = cvtpk(acc[mt][nt][2] + bval, acc[mt][nt][3] + bval);
        *(uint2*)&vd[((size_t)(mb * 16 + h) * 64 + d) * 2048 + t] =
            make_uint2(lo, hi);
      }
    } else if (wi == 0) {  // Q: pre-scaled by SC (softmax shift-invariance)
#pragma unroll
      for (int mt = 0; mt < 4; ++mt) {
#pragma unroll
        for (int i = 0; i < 4; ++i) {
          int m = m0 + wm + mt * 16 + lg * 4 + i;
          int mb = m >> 11, t = m & 2047;
          qd[((size_t)(mb * 16 + h) * 2048 + t) * 64 + d] =
              f2bf((acc[mt][nt][i] + bval) * SC);
        }
      }
    } else {
#pragma unroll
      for (int mt = 0; mt < 4; ++mt) {
#pragma unroll
        for (int i = 0; i < 4; ++i) {
          int m = m0 + wm + mt * 16 + lg * 4 + i;
          int mb = m >> 11, t = m & 2047;
          kd[((size_t)(mb * 16 + h) * 2048 + t) * 64 + d] =
              f2bf(acc[mt][nt][i] + bval);
        }
      }
    }
  }
}

// ---------------- proj 128x64 MFMA GEMM, BK=64, double-buffered ----------------
__global__ __launch_bounds__(256, 2) void gemm_proj_kernel(
    const u16* __restrict__ A, const u16* __restrict__ Bt,
    float* __restrict__ outf, const float* __restrict__ bias1) {
  __shared__ u16 Alds[2 * 8192];   // [2][128][64]
  __shared__ u16 Blds[2 * 4096];   // [2][64][64]
  int tid = threadIdx.x;
  int lane = tid & 63, w = tid >> 6;
  int l15 = lane & 15, lg = lane >> 4;
  int flat = blockIdx.x;
  int xcd = flat & 7, idx = flat >> 3;           // idx 0..63
  int rm = (xcd >> 1) * 8, rn = (xcd & 1) * 8;   // region: 8 mtiles x 8 ntiles
  int m0 = (rm + (idx & 7)) * 128, n0 = (rn + (idx >> 3)) * 64;
  int wm = (w >> 1) * 64, wn = (w & 1) * 32;
  int srow = lane >> 3;
  int colsw = ((lane & 7) * 8) ^ ((srow & 7) * 8);  // pre-swizzled source col

  const u16* pA[4];
  int dlsA[4];
#pragma unroll
  for (int j = 0; j < 4; ++j) {
    int issue = w * 4 + j;
    int row = issue * 8 + srow;
    pA[j] = A + (size_t)(m0 + row) * 1024 + colsw;
    dlsA[j] = issue * 512;
  }
  const u16* pB[2];
  int dlsB[2];
#pragma unroll
  for (int it = 0; it < 2; ++it) {
    int chunk = it * 256 + tid;
    int row = chunk >> 3;
    int col = ((chunk & 7) * 8) ^ ((row & 7) * 8);
    pB[it] = Bt + (size_t)(n0 + row) * 1024 + col;
    dlsB[it] = (it * 256 + w * 64) * 8;
  }
  int kx = (l15 & 7) << 4;
  int ofs0 = (lg * 16) ^ kx, ofs1 = (64 + lg * 16) ^ kx;
  int rbA = (wm + l15) * 128, rbB = (wn + l15) * 128;

  auto stage = [&](int buf) {
    u16* Ad = Alds + buf * 8192;
    u16* Bd = Blds + buf * 4096;
#pragma unroll
    for (int j = 0; j < 4; ++j) { gload16(pA[j], Ad + dlsA[j]); pA[j] += 64; }
#pragma unroll
    for (int it = 0; it < 2; ++it) { gload16(pB[it], Bd + dlsB[it]); pB[it] += 64; }
  };

  f32x4 acc[4][2] = {};
  stage(0);
  int cur = 0;
  for (int kt = 0; kt < 1024; kt += 64) {
    __syncthreads();  // drain vmcnt -> buf[cur] ready
    if (kt + 64 < 1024) stage(cur ^ 1);
    const char* Al = (const char*)Alds + cur * 16384;
    const char* Bl = (const char*)Blds + cur * 8192;
    __builtin_amdgcn_s_setprio(1);
#pragma unroll
    for (int kk = 0; kk < 2; ++kk) {
      int o_ = kk ? ofs1 : ofs0;
      short8 a[4], b[2];
#pragma unroll
      for (int mt = 0; mt < 4; ++mt)
        a[mt] = *(const short8*)(Al + (rbA + o_) + mt * 2048);
#pragma unroll
      for (int nt = 0; nt < 2; ++nt)
        b[nt] = *(const short8*)(Bl + (rbB + o_) + nt * 2048);
#pragma unroll
      for (int mt = 0; mt < 4; ++mt)
#pragma unroll
        for (int nt = 0; nt < 2; ++nt)
          acc[mt][nt] = __builtin_amdgcn_mfma_f32_16x16x32_bf16(a[mt], b[nt],
                                                                acc[mt][nt], 0, 0, 0);
    }
    __builtin_amdgcn_s_setprio(0);
    cur ^= 1;
  }
#pragma unroll
  for (int nt = 0; nt < 2; ++nt) {
    int n = n0 + wn + nt * 16 + l15;
    float bval = bias1[n];
#pragma unroll
    for (int mt = 0; mt < 4; ++mt) {
#pragma unroll
      for (int i = 0; i < 4; ++i) {
        int m = m0 + wm + mt * 16 + lg * 4 + i;
        outf[(size_t)m * 1024 + n] = acc[mt][nt][i] + bval;
      }
    }
  }
}

// ---------------- causal flash attention: shift-free + double-buffered --------
// R17's shift-free softmax (best) on R9's proven dbuf skeleton: prologue
// stage; per tile ONE barrier -> prefetch next tile into buf^1 -> compute
// buf. Prefetch returns under the MFMA+exp compute instead of serializing at
// a second barrier. LDS 40KB (Kdbuf16+Vdbuf16+P8) -> 4 blocks/CU (grid-
// limited, same as R17). Complementary schedule; Q pre-scaled upstream.
__global__ __launch_bounds__(256, 4) void fattn_kernel(const u16* __restrict__ qb,
                                                       const u16* __restrict__ kb,
                                                       const u16* __restrict__ vt,
                                                       u16* __restrict__ y) {
  __shared__ u16 Klds[2 * 4096];
  __shared__ u16 Vlds[2 * 4096];   // V^T: [d][kv], swizzled
  __shared__ u16 Plds[4 * 1024];
  int tid = threadIdx.x, lane = tid & 63, w = tid >> 6;
  int l15 = lane & 15, lg = lane >> 4;
  int flat = blockIdx.x;
  int bh = flat & 31;
  int g = flat >> 5;                  // dispatch round group 0..31
  int qt;
  switch (g >> 3) {                   // complementary rounds: 31..24,0..7,23..16,8..15
    case 0:  qt = 31 - g; break;
    case 1:  qt = g - 8;  break;
    case 2:  qt = 39 - g; break;
    default: qt = g - 16; break;
  }
  size_t base = (size_t)bh * 2048 * 64;
  int mb = bh >> 4, h = bh & 15;

  // ---- hoisted staging geometry (advance per tile: K +4096, V +64 elem) ----
  int r0 = tid >> 3, c0 = ((tid & 7) * 8) ^ ((r0 & 7) << 3);
  int r1 = (256 + tid) >> 3, c1 = ((tid & 7) * 8) ^ ((r1 & 7) << 3);
  const u16* pK0 = kb + base + (size_t)r0 * 64 + c0;
  const u16* pK1 = kb + base + (size_t)r1 * 64 + c1;
  const u16* pV0 = vt + base + (size_t)r0 * 2048 + c0;
  const u16* pV1 = vt + base + (size_t)r1 * 2048 + c1;
  int dk0 = w * 512, dk1 = (256 + w * 64) * 8;   // LDS dest offsets (u16)
  // ---- hoisted LDS read bases (bytes); shared by K, V, P reads ----
  int kx = (l15 & 7) << 4;
  int rb0 = l15 * 128 + ((lg * 16) ^ kx);
  int rb1 = l15 * 128 + ((64 + lg * 16) ^ kx);
  char* pbase = (char*)Plds + w * 2048;
  int pw0 = l15 * 128 + ((lg * 8) ^ kx);
  int pw1 = l15 * 128 + ((32 + lg * 8) ^ kx);
  int pw2 = l15 * 128 + ((64 + lg * 8) ^ kx);
  int pw3 = l15 * 128 + ((96 + lg * 8) ^ kx);

  int qw = qt * 64 + w * 16;
  int qr = qw + l15;
  short8 qf[2];
#pragma unroll
  for (int kk = 0; kk < 2; ++kk)
    qf[kk] = *(const short8*)&qb[base + (size_t)qr * 64 + kk * 32 + lg * 8];
  f32x4 o[4] = {};
  float lrow = 0.f;
  {  // prologue stage tile 0 into buf 0
    gload16(pK0, Klds + dk0); gload16(pK1, Klds + dk1);
    gload16(pV0, Vlds + dk0); gload16(pV1, Vlds + dk1);
    pK0 += 4096; pK1 += 4096; pV0 += 64; pV1 += 64;
  }
  int cb = 0;
  int ntiles = qt + 1;
  for (int j = 0; j < ntiles; ++j) {
    __syncthreads();  // drains vmcnt: buf[cb] ready; prev reads of cb^1 done
    if (j + 1 < ntiles) {  // prefetch next tile into cb^1 (returns under compute)
      u16* kd_ = Klds + (cb ^ 1) * 4096;
      u16* vd_ = Vlds + (cb ^ 1) * 4096;
      gload16(pK0, kd_ + dk0); gload16(pK1, kd_ + dk1);
      gload16(pV0, vd_ + dk0); gload16(pV1, vd_ + dk1);
      pK0 += 4096; pK1 += 4096; pV0 += 64; pV1 += 64;
    }
    const char* kl = (const char*)Klds + cb * 8192;
    const char* vl = (const char*)Vlds + cb * 8192;
    // S^T = K Q^T  (swapped operands; Q pre-scaled by 0.125*log2e)
    f32x4 s[4] = {};
    __builtin_amdgcn_s_setprio(1);
#pragma unroll
    for (int kk = 0; kk < 2; ++kk) {
      int o_ = kk ? rb1 : rb0;
      short8 ka[4];
#pragma unroll
      for (int nt = 0; nt < 4; ++nt)
        ka[nt] = *(const short8*)(kl + o_ + nt * 2048);
#pragma unroll
      for (int nt = 0; nt < 4; ++nt)
        s[nt] = __builtin_amdgcn_mfma_f32_16x16x32_bf16(ka[nt], qf[kk], s[nt], 0, 0, 0);
    }
    __builtin_amdgcn_s_setprio(0);
    // p = exp2(s) directly (shift-free); masked entries -> 0
    float p[16];
    if (j == qt) {
      int k0 = j * 64;
#pragma unroll
      for (int nt = 0; nt < 4; ++nt)
#pragma unroll
        for (int i = 0; i < 4; ++i) {
          int ka_ = k0 + nt * 16 + lg * 4 + i;
          p[nt * 4 + i] = (ka_ > qr) ? 0.f : exp2f(s[nt][i]);
        }
    } else {
#pragma unroll
      for (int nt = 0; nt < 4; ++nt)
#pragma unroll
        for (int i = 0; i < 4; ++i) p[nt * 4 + i] = exp2f(s[nt][i]);
    }
    float pr0 = ((p[0] + p[1]) + (p[2] + p[3])) + ((p[4] + p[5]) + (p[6] + p[7]));
    float pr1 = ((p[8] + p[9]) + (p[10] + p[11])) + ((p[12] + p[13]) + (p[14] + p[15]));
    lrow += pr0 + pr1;  // per-lane partial; reduced after the loop
    // P[q][k] -> LDS, packed b64 (4 consecutive k per write)
    *(uint2*)(pbase + pw0) = make_uint2(cvtpk(p[0], p[1]), cvtpk(p[2], p[3]));
    *(uint2*)(pbase + pw1) = make_uint2(cvtpk(p[4], p[5]), cvtpk(p[6], p[7]));
    *(uint2*)(pbase + pw2) = make_uint2(cvtpk(p[8], p[9]), cvtpk(p[10], p[11]));
    *(uint2*)(pbase + pw3) = make_uint2(cvtpk(p[12], p[13]), cvtpk(p[14], p[15]));
    // O^T += V^T P^T  (swapped operands)
    __builtin_amdgcn_s_setprio(1);
#pragma unroll
    for (int kk = 0; kk < 2; ++kk) {
      int o_ = kk ? rb1 : rb0;
      short8 ap = *(const short8*)(pbase + o_);
#pragma unroll
      for (int dn = 0; dn < 4; ++dn) {
        short8 bv_ = *(const short8*)(vl + o_ + dn * 2048);
        o[dn] = __builtin_amdgcn_mfma_f32_16x16x32_bf16(bv_, ap, o[dn], 0, 0, 0);
      }
    }
    __builtin_amdgcn_s_setprio(0);
    cb ^= 1;
  }
  // combine lrow partials across the 4 lane-groups of each q-row
  lrow += __shfl_xor(lrow, 16);
  lrow += __shfl_xor(lrow, 32);
  float inv = 1.f / lrow;
  size_t rb = ((size_t)(mb * 2048 + qr)) * 1024 + (size_t)h * 64;
#pragma unroll
  for (int dn = 0; dn < 4; ++dn) {
    unsigned lo = cvtpk(o[dn][0] * inv, o[dn][1] * inv);
    unsigned hi = cvtpk(o[dn][2] * inv, o[dn][3] * inv);
    *(uint2*)&y[rb + dn * 16 + lg * 4] = make_uint2(lo, hi);
  }
}

extern "C" void kernel_launch(void* const* d_in, const int* in_sizes, int n_in,
                              void* d_out, int out_size, void* d_ws, size_t ws_size,
                              hipStream_t stream) {
  const float* x  = (const float*)d_in[0];
  const float* Wq = (const float*)d_in[1];
  const float* bq = (const float*)d_in[2];
  const float* Wk = (const float*)d_in[3];
  const float* bk = (const float*)d_in[4];
  const float* Wv = (const float*)d_in[5];
  const float* bv = (const float*)d_in[6];
  const float* Wp = (const float*)d_in[7];
  const float* bp = (const float*)d_in[8];
  float* out = (float*)d_out;
  char* ws = (char*)d_ws;
  u16* xb   = (u16*)(ws);
  u16* wt   = (u16*)(ws + ((size_t)8 << 20));
  u16* qbuf = (u16*)(ws + ((size_t)16 << 20));
  u16* kbuf = (u16*)(ws + ((size_t)24 << 20));
  u16* vtb  = (u16*)(ws + ((size_t)32 << 20));  // V^T written by QKV epilogue
  u16* ybuf = (u16*)(ws + ((size_t)40 << 20));

  prep_kernel<<<dim3(3072), dim3(256), 0, stream>>>(x, Wq, Wk, Wv, Wp, xb, wt);
  // QKV: M=4096 (GM=32), N=3072 (GN=24); per-XCD region 8x12; single-buffered
  gemm_qkv_kernel<<<dim3(768), dim3(256), 0, stream>>>(
      xb, wt, 1024, 32, 24, 8, 12, qbuf, kbuf, vtb, bq, bk, bv);
  fattn_kernel<<<dim3(1024), dim3(256), 0, stream>>>(qbuf, kbuf, vtb, ybuf);
  // proj: 128x64 tiles, grid 512 (2 blocks/CU co-resident), double-buffered
  gemm_proj_kernel<<<dim3(512), dim3(256), 0, stream>>>(
      ybuf, wt + (size_t)3 * 1024 * 1024, out, bp);
  (void)in_sizes; (void)n_in; (void)out_size; (void)ws_size;
}

// Round 20
// 94.538 us; speedup vs baseline: 1.1840x; 1.0330x over previous
//
#include <hip/hip_runtime.h>
#include <hip/hip_bf16.h>
#include <stdint.h>

typedef unsigned short u16;
typedef __attribute__((ext_vector_type(8))) short short8;
typedef __attribute__((ext_vector_type(4))) float f32x4;

// ws layout (bytes): [0,8M) x_bf16 [8M,16M) Wt(4x1Mx2B) [16M,24M) q
// [24M,32M) k [32M,40M) v^T [B,H,D,T] [40M,48M) y
static __device__ __forceinline__ u16 f2bf(float f) {
  unsigned u = __builtin_bit_cast(unsigned, f);
  u += 0x7fffu + ((u >> 16) & 1u);
  return (u16)(u >> 16);
}

static __device__ __forceinline__ unsigned cvtpk(float lo, float hi) {
  unsigned r;
  asm("v_cvt_pk_bf16_f32 %0, %1, %2" : "=v"(r) : "v"(lo), "v"(hi));
  return r;
}

// raw v_exp_f32 (2^x). OCML's exp2f adds a ~7-op range-reduction wrapper we
// don't need (inputs bounded, threshold is bf16-scale). s_nop 1 covers the
// TRANS->consumer wait-state hazard the compiler can't see through asm.
static __device__ __forceinline__ float exp2_raw(float x) {
  float r;
  asm("v_exp_f32 %0, %1\n\ts_nop 1" : "=v"(r) : "v"(x));
  return r;
}

static __device__ __forceinline__ void gload16(const u16* g, u16* l) {
  __builtin_amdgcn_global_load_lds(
      (__attribute__((address_space(1))) void*)const_cast<u16*>(g),
      (__attribute__((address_space(3))) void*)l, 16, 0, 0);
}

// ---------------- fused prep: x fp32->bf16 (blocks 0..2047) +
//                  W [k][n] fp32 -> Wt [n][k] bf16 (blocks 2048..3071) ----------
__global__ __launch_bounds__(256) void prep_kernel(
    const float* __restrict__ x, const float* __restrict__ Wq,
    const float* __restrict__ Wk, const float* __restrict__ Wv,
    const float* __restrict__ Wp, u16* __restrict__ xb, u16* __restrict__ wt) {
  __shared__ float tile[64][65];
  int b = blockIdx.x;
  if (b < 2048) {
    size_t i = (size_t)b * 256 + threadIdx.x;  // 8 floats per thread
    const float4* xp = (const float4*)x + i * 2;
    float4 a = xp[0], v = xp[1];
    union { u16 u[8]; int4 q; } r;
    r.u[0] = f2bf(a.x); r.u[1] = f2bf(a.y); r.u[2] = f2bf(a.z); r.u[3] = f2bf(a.w);
    r.u[4] = f2bf(v.x); r.u[5] = f2bf(v.y); r.u[6] = f2bf(v.z); r.u[7] = f2bf(v.w);
    *(int4*)(xb + i * 8) = r.q;
  } else {
    int wb = b - 2048;
    int wz = wb >> 8, r8 = wb & 255;
    const float* W = (wz == 0) ? Wq : (wz == 1) ? Wk : (wz == 2) ? Wv : Wp;
    int n0 = (r8 & 15) * 64, k0 = (r8 >> 4) * 64;
    int tx = threadIdx.x & 63, ty = threadIdx.x >> 6;
#pragma unroll
    for (int r = 0; r < 16; ++r)
      tile[ty + 4 * r][tx] = W[(size_t)(k0 + ty + 4 * r) * 1024 + n0 + tx];
    __syncthreads();
    u16* dst = wt + (size_t)wz * 1024 * 1024;
#pragma unroll
    for (int r = 0; r < 16; ++r) {
      int n = ty + 4 * r;
      dst[(size_t)(n0 + n) * 1024 + k0 + tx] = f2bf(tile[tx][n]);
    }
  }
}

// ---------------- QKV 128x128 MFMA GEMM, BK=64, single-buffered ----------------
// Q output is pre-scaled by 0.125*log2(e) so fattn's exp2 consumes raw MFMA S.
__global__ __launch_bounds__(256, 2) void gemm_qkv_kernel(
    const u16* __restrict__ A, const u16* __restrict__ Bt, int Kdim,
    int GM, int GN, int RM, int RN,
    u16* __restrict__ qd, u16* __restrict__ kd, u16* __restrict__ vd,
    const float* __restrict__ bq, const float* __restrict__ bk,
    const float* __restrict__ bv) {
  __shared__ u16 Alds[8192];
  __shared__ u16 Blds[8192];
  int tid = threadIdx.x;
  int lane = tid & 63, w = tid >> 6;
  int l15 = lane & 15, lg = lane >> 4;
  int flat = blockIdx.x;
  int xcd = flat & 7, idx = flat >> 3;
  int rnc = GN / RN;
  int rm = (xcd / rnc) * RM, rn = (xcd % rnc) * RN;
  int im = idx % RM, in_ = idx / RM;
  int m0 = (rm + im) * 128, n0 = (rn + in_) * 128;
  int wm = (w >> 1) * 64, wn = (w & 1) * 64;
  int srow = lane >> 3;
  int colsw = ((lane & 7) * 8) ^ ((srow & 7) * 8);  // pre-swizzled source col
  const float SC = 0.125f * 1.44269504088896340736f;

  const u16* pA[4];
  const u16* pB[4];
  int dls[4];
#pragma unroll
  for (int j = 0; j < 4; ++j) {
    int issue = w * 4 + j;
    int row = issue * 8 + srow;
    pA[j] = A + (size_t)(m0 + row) * Kdim + colsw;
    pB[j] = Bt + (size_t)(n0 + row) * Kdim + colsw;
    dls[j] = issue * 512;
  }
  int kx = (l15 & 7) << 4;
  int ofs0 = (lg * 16) ^ kx, ofs1 = (64 + lg * 16) ^ kx;
  int rbA = (wm + l15) * 128, rbB = (wn + l15) * 128;

  f32x4 acc[4][4] = {};
  for (int kt = 0; kt < Kdim; kt += 64) {
#pragma unroll
    for (int j = 0; j < 4; ++j) {
      gload16(pA[j], Alds + dls[j]);
      gload16(pB[j], Blds + dls[j]);
      pA[j] += 64; pB[j] += 64;
    }
    __syncthreads();  // drain vmcnt -> buf ready
    __builtin_amdgcn_s_setprio(1);
#pragma unroll
    for (int kk = 0; kk < 2; ++kk) {
      int o_ = kk ? ofs1 : ofs0;
      short8 a[4], b[4];
#pragma unroll
      for (int mt = 0; mt < 4; ++mt)
        a[mt] = *(const short8*)((const char*)Alds + (rbA + o_) + mt * 2048);
#pragma unroll
      for (int nt = 0; nt < 4; ++nt)
        b[nt] = *(const short8*)((const char*)Blds + (rbB + o_) + nt * 2048);
#pragma unroll
      for (int mt = 0; mt < 4; ++mt)
#pragma unroll
        for (int nt = 0; nt < 4; ++nt)
          acc[mt][nt] = __builtin_amdgcn_mfma_f32_16x16x32_bf16(a[mt], b[nt],
                                                                acc[mt][nt], 0, 0, 0);
    }
    __builtin_amdgcn_s_setprio(0);
    __syncthreads();  // all waves done reading before next stage
  }
#pragma unroll
  for (int nt = 0; nt < 4; ++nt) {
    int n = n0 + wn + nt * 16 + l15;
    int wi = n >> 10, nn = n & 1023, h = nn >> 6, d = nn & 63;
    const float* bb = (wi == 0) ? bq : (wi == 1) ? bk : bv;
    float bval = bb[nn];
    if (wi == 2) {  // V: write transposed [B,H,D,T], 4 consecutive t -> uint2
#pragma unroll
      for (int mt = 0; mt < 4; ++mt) {
        int m = m0 + wm + mt * 16 + lg * 4;
        int mb = m >> 11, t = m & 2047;
        unsigned lo = cvtpk(acc[mt][nt][0] + bval, acc[mt][nt][1] + bval);
        unsigned hi = cvtpk(acc[mt][nt][2] + bval, acc[mt][nt][3] + bval);
        *(uint2*)&vd[((size_t)(mb * 16 + h) * 64 + d) * 2048 + t] =
            make_uint2(lo, hi);
      }
    } else if (wi == 0) {  // Q: pre-scaled by SC (softmax shift-invariance)
#pragma unroll
      for (int mt = 0; mt < 4; ++mt) {
#pragma unroll
        for (int i = 0; i < 4; ++i) {
          int m = m0 + wm + mt * 16 + lg * 4 + i;
          int mb = m >> 11, t = m & 2047;
          qd[((size_t)(mb * 16 + h) * 2048 + t) * 64 + d] =
              f2bf((acc[mt][nt][i] + bval) * SC);
        }
      }
    } else {
#pragma unroll
      for (int mt = 0; mt < 4; ++mt) {
#pragma unroll
        for (int i = 0; i < 4; ++i) {
          int m = m0 + wm + mt * 16 + lg * 4 + i;
          int mb = m >> 11, t = m & 2047;
          kd[((size_t)(mb * 16 + h) * 2048 + t) * 64 + d] =
              f2bf(acc[mt][nt][i] + bval);
        }
      }
    }
  }
}

// ---------------- proj 128x64 MFMA GEMM, BK=64, double-buffered ----------------
__global__ __launch_bounds__(256, 2) void gemm_proj_kernel(
    const u16* __restrict__ A, const u16* __restrict__ Bt,
    float* __restrict__ outf, const float* __restrict__ bias1) {
  __shared__ u16 Alds[2 * 8192];   // [2][128][64]
  __shared__ u16 Blds[2 * 4096];   // [2][64][64]
  int tid = threadIdx.x;
  int lane = tid & 63, w = tid >> 6;
  int l15 = lane & 15, lg = lane >> 4;
  int flat = blockIdx.x;
  int xcd = flat & 7, idx = flat >> 3;           // idx 0..63
  int rm = (xcd >> 1) * 8, rn = (xcd & 1) * 8;   // region: 8 mtiles x 8 ntiles
  int m0 = (rm + (idx & 7)) * 128, n0 = (rn + (idx >> 3)) * 64;
  int wm = (w >> 1) * 64, wn = (w & 1) * 32;
  int srow = lane >> 3;
  int colsw = ((lane & 7) * 8) ^ ((srow & 7) * 8);  // pre-swizzled source col

  const u16* pA[4];
  int dlsA[4];
#pragma unroll
  for (int j = 0; j < 4; ++j) {
    int issue = w * 4 + j;
    int row = issue * 8 + srow;
    pA[j] = A + (size_t)(m0 + row) * 1024 + colsw;
    dlsA[j] = issue * 512;
  }
  const u16* pB[2];
  int dlsB[2];
#pragma unroll
  for (int it = 0; it < 2; ++it) {
    int chunk = it * 256 + tid;
    int row = chunk >> 3;
    int col = ((chunk & 7) * 8) ^ ((row & 7) * 8);
    pB[it] = Bt + (size_t)(n0 + row) * 1024 + col;
    dlsB[it] = (it * 256 + w * 64) * 8;
  }
  int kx = (l15 & 7) << 4;
  int ofs0 = (lg * 16) ^ kx, ofs1 = (64 + lg * 16) ^ kx;
  int rbA = (wm + l15) * 128, rbB = (wn + l15) * 128;

  auto stage = [&](int buf) {
    u16* Ad = Alds + buf * 8192;
    u16* Bd = Blds + buf * 4096;
#pragma unroll
    for (int j = 0; j < 4; ++j) { gload16(pA[j], Ad + dlsA[j]); pA[j] += 64; }
#pragma unroll
    for (int it = 0; it < 2; ++it) { gload16(pB[it], Bd + dlsB[it]); pB[it] += 64; }
  };

  f32x4 acc[4][2] = {};
  stage(0);
  int cur = 0;
  for (int kt = 0; kt < 1024; kt += 64) {
    __syncthreads();  // drain vmcnt -> buf[cur] ready
    if (kt + 64 < 1024) stage(cur ^ 1);
    const char* Al = (const char*)Alds + cur * 16384;
    const char* Bl = (const char*)Blds + cur * 8192;
    __builtin_amdgcn_s_setprio(1);
#pragma unroll
    for (int kk = 0; kk < 2; ++kk) {
      int o_ = kk ? ofs1 : ofs0;
      short8 a[4], b[2];
#pragma unroll
      for (int mt = 0; mt < 4; ++mt)
        a[mt] = *(const short8*)(Al + (rbA + o_) + mt * 2048);
#pragma unroll
      for (int nt = 0; nt < 2; ++nt)
        b[nt] = *(const short8*)(Bl + (rbB + o_) + nt * 2048);
#pragma unroll
      for (int mt = 0; mt < 4; ++mt)
#pragma unroll
        for (int nt = 0; nt < 2; ++nt)
          acc[mt][nt] = __builtin_amdgcn_mfma_f32_16x16x32_bf16(a[mt], b[nt],
                                                                acc[mt][nt], 0, 0, 0);
    }
    __builtin_amdgcn_s_setprio(0);
    cur ^= 1;
  }
#pragma unroll
  for (int nt = 0; nt < 2; ++nt) {
    int n = n0 + wn + nt * 16 + l15;
    float bval = bias1[n];
#pragma unroll
    for (int mt = 0; mt < 4; ++mt) {
#pragma unroll
      for (int i = 0; i < 4; ++i) {
        int m = m0 + wm + mt * 16 + lg * 4 + i;
        outf[(size_t)m * 1024 + n] = acc[mt][nt][i] + bval;
      }
    }
  }
}

// ---------------- causal flash attention: shift-free + dbuf + raw v_exp -------
// R19 structure (best). exp2f -> raw v_exp_f32 (drops OCML's ~7-op range
// wrapper per call: 16 calls/tile was ~1/3 of the VALU budget). P writes
// issued before the lrow sum so ds latency overlaps the adds.
__global__ __launch_bounds__(256, 4) void fattn_kernel(const u16* __restrict__ qb,
                                                       const u16* __restrict__ kb,
                                                       const u16* __restrict__ vt,
                                                       u16* __restrict__ y) {
  __shared__ u16 Klds[2 * 4096];
  __shared__ u16 Vlds[2 * 4096];   // V^T: [d][kv], swizzled
  __shared__ u16 Plds[4 * 1024];
  int tid = threadIdx.x, lane = tid & 63, w = tid >> 6;
  int l15 = lane & 15, lg = lane >> 4;
  int flat = blockIdx.x;
  int bh = flat & 31;
  int g = flat >> 5;                  // dispatch round group 0..31
  int qt;
  switch (g >> 3) {                   // complementary rounds: 31..24,0..7,23..16,8..15
    case 0:  qt = 31 - g; break;
    case 1:  qt = g - 8;  break;
    case 2:  qt = 39 - g; break;
    default: qt = g - 16; break;
  }
  size_t base = (size_t)bh * 2048 * 64;
  int mb = bh >> 4, h = bh & 15;

  // ---- hoisted staging geometry (advance per tile: K +4096, V +64 elem) ----
  int r0 = tid >> 3, c0 = ((tid & 7) * 8) ^ ((r0 & 7) << 3);
  int r1 = (256 + tid) >> 3, c1 = ((tid & 7) * 8) ^ ((r1 & 7) << 3);
  const u16* pK0 = kb + base + (size_t)r0 * 64 + c0;
  const u16* pK1 = kb + base + (size_t)r1 * 64 + c1;
  const u16* pV0 = vt + base + (size_t)r0 * 2048 + c0;
  const u16* pV1 = vt + base + (size_t)r1 * 2048 + c1;
  int dk0 = w * 512, dk1 = (256 + w * 64) * 8;   // LDS dest offsets (u16)
  // ---- hoisted LDS read bases (bytes); shared by K, V, P reads ----
  int kx = (l15 & 7) << 4;
  int rb0 = l15 * 128 + ((lg * 16) ^ kx);
  int rb1 = l15 * 128 + ((64 + lg * 16) ^ kx);
  char* pbase = (char*)Plds + w * 2048;
  int pw0 = l15 * 128 + ((lg * 8) ^ kx);
  int pw1 = l15 * 128 + ((32 + lg * 8) ^ kx);
  int pw2 = l15 * 128 + ((64 + lg * 8) ^ kx);
  int pw3 = l15 * 128 + ((96 + lg * 8) ^ kx);

  int qw = qt * 64 + w * 16;
  int qr = qw + l15;
  short8 qf[2];
#pragma unroll
  for (int kk = 0; kk < 2; ++kk)
    qf[kk] = *(const short8*)&qb[base + (size_t)qr * 64 + kk * 32 + lg * 8];
  f32x4 o[4] = {};
  float lrow = 0.f;
  {  // prologue stage tile 0 into buf 0
    gload16(pK0, Klds + dk0); gload16(pK1, Klds + dk1);
    gload16(pV0, Vlds + dk0); gload16(pV1, Vlds + dk1);
    pK0 += 4096; pK1 += 4096; pV0 += 64; pV1 += 64;
  }
  int cb = 0;
  int ntiles = qt + 1;
  for (int j = 0; j < ntiles; ++j) {
    __syncthreads();  // drains vmcnt: buf[cb] ready; prev reads of cb^1 done
    if (j + 1 < ntiles) {  // prefetch next tile into cb^1 (returns under compute)
      u16* kd_ = Klds + (cb ^ 1) * 4096;
      u16* vd_ = Vlds + (cb ^ 1) * 4096;
      gload16(pK0, kd_ + dk0); gload16(pK1, kd_ + dk1);
      gload16(pV0, vd_ + dk0); gload16(pV1, vd_ + dk1);
      pK0 += 4096; pK1 += 4096; pV0 += 64; pV1 += 64;
    }
    const char* kl = (const char*)Klds + cb * 8192;
    const char* vl = (const char*)Vlds + cb * 8192;
    // S^T = K Q^T  (swapped operands; Q pre-scaled by 0.125*log2e)
    f32x4 s[4] = {};
    __builtin_amdgcn_s_setprio(1);
#pragma unroll
    for (int kk = 0; kk < 2; ++kk) {
      int o_ = kk ? rb1 : rb0;
      short8 ka[4];
#pragma unroll
      for (int nt = 0; nt < 4; ++nt)
        ka[nt] = *(const short8*)(kl + o_ + nt * 2048);
#pragma unroll
      for (int nt = 0; nt < 4; ++nt)
        s[nt] = __builtin_amdgcn_mfma_f32_16x16x32_bf16(ka[nt], qf[kk], s[nt], 0, 0, 0);
    }
    __builtin_amdgcn_s_setprio(0);
    // p = 2^s via raw v_exp_f32 (shift-free); masked entries -> 0
    float p[16];
    if (j == qt) {
      int k0 = j * 64;
#pragma unroll
      for (int nt = 0; nt < 4; ++nt)
#pragma unroll
        for (int i = 0; i < 4; ++i) {
          int ka_ = k0 + nt * 16 + lg * 4 + i;
          p[nt * 4 + i] = (ka_ > qr) ? 0.f : exp2_raw(s[nt][i]);
        }
    } else {
#pragma unroll
      for (int nt = 0; nt < 4; ++nt)
#pragma unroll
        for (int i = 0; i < 4; ++i) p[nt * 4 + i] = exp2_raw(s[nt][i]);
    }
    // P[q][k] -> LDS first (ds latency overlaps the lrow adds below)
    *(uint2*)(pbase + pw0) = make_uint2(cvtpk(p[0], p[1]), cvtpk(p[2], p[3]));
    *(uint2*)(pbase + pw1) = make_uint2(cvtpk(p[4], p[5]), cvtpk(p[6], p[7]));
    *(uint2*)(pbase + pw2) = make_uint2(cvtpk(p[8], p[9]), cvtpk(p[10], p[11]));
    *(uint2*)(pbase + pw3) = make_uint2(cvtpk(p[12], p[13]), cvtpk(p[14], p[15]));
    float pr0 = ((p[0] + p[1]) + (p[2] + p[3])) + ((p[4] + p[5]) + (p[6] + p[7]));
    float pr1 = ((p[8] + p[9]) + (p[10] + p[11])) + ((p[12] + p[13]) + (p[14] + p[15]));
    lrow += pr0 + pr1;  // per-lane partial; reduced after the loop
    // O^T += V^T P^T  (swapped operands)
    __builtin_amdgcn_s_setprio(1);
#pragma unroll
    for (int kk = 0; kk < 2; ++kk) {
      int o_ = kk ? rb1 : rb0;
      short8 ap = *(const short8*)(pbase + o_);
#pragma unroll
      for (int dn = 0; dn < 4; ++dn) {
        short8 bv_ = *(const short8*)(vl + o_ + dn * 2048);
        o[dn] = __builtin_amdgcn_mfma_f32_16x16x32_bf16(bv_, ap, o[dn], 0, 0, 0);
      }
    }
    __builtin_amdgcn_s_setprio(0);
    cb ^= 1;
  }
  // combine lrow partials across the 4 lane-groups of each q-row
  lrow += __shfl_xor(lrow, 16);
  lrow += __shfl_xor(lrow, 32);
  float inv = 1.f / lrow;
  size_t rb = ((size_t)(mb * 2048 + qr)) * 1024 + (size_t)h * 64;
#pragma unroll
  for (int dn = 0; dn < 4; ++dn) {
    unsigned lo = cvtpk(o[dn][0] * inv, o[dn][1] * inv);
    unsigned hi = cvtpk(o[dn][2] * inv, o[dn][3] * inv);
    *(uint2*)&y[rb + dn * 16 + lg * 4] = make_uint2(lo, hi);
  }
}

extern "C" void kernel_launch(void* const* d_in, const int* in_sizes, int n_in,
                              void* d_out, int out_size, void* d_ws, size_t ws_size,
                              hipStream_t stream) {
  const float* x  = (const float*)d_in[0];
  const float* Wq = (const float*)d_in[1];
  const float* bq = (const float*)d_in[2];
  const float* Wk = (const float*)d_in[3];
  const float* bk = (const float*)d_in[4];
  const float* Wv = (const float*)d_in[5];
  const float* bv = (const float*)d_in[6];
  const float* Wp = (const float*)d_in[7];
  const float* bp = (const float*)d_in[8];
  float* out = (float*)d_out;
  char* ws = (char*)d_ws;
  u16* xb   = (u16*)(ws);
  u16* wt   = (u16*)(ws + ((size_t)8 << 20));
  u16* qbuf = (u16*)(ws + ((size_t)16 << 20));
  u16* kbuf = (u16*)(ws + ((size_t)24 << 20));
  u16* vtb  = (u16*)(ws + ((size_t)32 << 20));  // V^T written by QKV epilogue
  u16* ybuf = (u16*)(ws + ((size_t)40 << 20));

  prep_kernel<<<dim3(3072), dim3(256), 0, stream>>>(x, Wq, Wk, Wv, Wp, xb, wt);
  // QKV: M=4096 (GM=32), N=3072 (GN=24); per-XCD region 8x12; single-buffered
  gemm_qkv_kernel<<<dim3(768), dim3(256), 0, stream>>>(
      xb, wt, 1024, 32, 24, 8, 12, qbuf, kbuf, vtb, bq, bk, bv);
  fattn_kernel<<<dim3(1024), dim3(256), 0, stream>>>(qbuf, kbuf, vtb, ybuf);
  // proj: 128x64 tiles, grid 512 (2 blocks/CU co-resident), double-buffered
  gemm_proj_kernel<<<dim3(512), dim3(256), 0, stream>>>(
      ybuf, wt + (size_t)3 * 1024 * 1024, out, bp);
  (void)in_sizes; (void)n_in; (void)out_size; (void)ws_size;
}

// Round 21
// 93.381 us; speedup vs baseline: 1.1987x; 1.0124x over previous
//
#include <hip/hip_runtime.h>
#include <hip/hip_bf16.h>
#include <stdint.h>

typedef unsigned short u16;
typedef __attribute__((ext_vector_type(8))) short short8;
typedef __attribute__((ext_vector_type(4))) float f32x4;

// ws layout (bytes): [0,8M) x_bf16 [8M,16M) Wt(4x1Mx2B) [16M,24M) q
// [24M,32M) k [32M,40M) v^T [B,H,D,T] [40M,48M) y
static __device__ __forceinline__ u16 f2bf(float f) {
  unsigned u = __builtin_bit_cast(unsigned, f);
  u += 0x7fffu + ((u >> 16) & 1u);
  return (u16)(u >> 16);
}

static __device__ __forceinline__ unsigned cvtpk(float lo, float hi) {
  unsigned r;
  asm("v_cvt_pk_bf16_f32 %0, %1, %2" : "=v"(r) : "v"(lo), "v"(hi));
  return r;
}

static __device__ __forceinline__ void gload16(const u16* g, u16* l) {
  __builtin_amdgcn_global_load_lds(
      (__attribute__((address_space(1))) void*)const_cast<u16*>(g),
      (__attribute__((address_space(3))) void*)l, 16, 0, 0);
}

// ---------------- fused prep: x fp32->bf16 (blocks 0..2047) +
//                  W [k][n] fp32 -> Wt [n][k] bf16 (blocks 2048..3071) ----------
__global__ __launch_bounds__(256) void prep_kernel(
    const float* __restrict__ x, const float* __restrict__ Wq,
    const float* __restrict__ Wk, const float* __restrict__ Wv,
    const float* __restrict__ Wp, u16* __restrict__ xb, u16* __restrict__ wt) {
  __shared__ float tile[64][65];
  int b = blockIdx.x;
  if (b < 2048) {
    size_t i = (size_t)b * 256 + threadIdx.x;  // 8 floats per thread
    const float4* xp = (const float4*)x + i * 2;
    float4 a = xp[0], v = xp[1];
    union { u16 u[8]; int4 q; } r;
    r.u[0] = f2bf(a.x); r.u[1] = f2bf(a.y); r.u[2] = f2bf(a.z); r.u[3] = f2bf(a.w);
    r.u[4] = f2bf(v.x); r.u[5] = f2bf(v.y); r.u[6] = f2bf(v.z); r.u[7] = f2bf(v.w);
    *(int4*)(xb + i * 8) = r.q;
  } else {
    int wb = b - 2048;
    int wz = wb >> 8, r8 = wb & 255;
    const float* W = (wz == 0) ? Wq : (wz == 1) ? Wk : (wz == 2) ? Wv : Wp;
    int n0 = (r8 & 15) * 64, k0 = (r8 >> 4) * 64;
    int tx = threadIdx.x & 63, ty = threadIdx.x >> 6;
#pragma unroll
    for (int r = 0; r < 16; ++r)
      tile[ty + 4 * r][tx] = W[(size_t)(k0 + ty + 4 * r) * 1024 + n0 + tx];
    __syncthreads();
    u16* dst = wt + (size_t)wz * 1024 * 1024;
#pragma unroll
    for (int r = 0; r < 16; ++r) {
      int n = ty + 4 * r;
      dst[(size_t)(n0 + n) * 1024 + k0 + tx] = f2bf(tile[tx][n]);
    }
  }
}

// ---------------- QKV 128x128 MFMA GEMM, BK=64, single-buffered ----------------
// Q output is pre-scaled by 0.125*log2(e) so fattn's exp2 consumes raw MFMA S.
__global__ __launch_bounds__(256, 2) void gemm_qkv_kernel(
    const u16* __restrict__ A, const u16* __restrict__ Bt, int Kdim,
    int GM, int GN, int RM, int RN,
    u16* __restrict__ qd, u16* __restrict__ kd, u16* __restrict__ vd,
    const float* __restrict__ bq, const float* __restrict__ bk,
    const float* __restrict__ bv) {
  __shared__ u16 Alds[8192];
  __shared__ u16 Blds[8192];
  int tid = threadIdx.x;
  int lane = tid & 63, w = tid >> 6;
  int l15 = lane & 15, lg = lane >> 4;
  int flat = blockIdx.x;
  int xcd = flat & 7, idx = flat >> 3;
  int rnc = GN / RN;
  int rm = (xcd / rnc) * RM, rn = (xcd % rnc) * RN;
  int im = idx % RM, in_ = idx / RM;
  int m0 = (rm + im) * 128, n0 = (rn + in_) * 128;
  int wm = (w >> 1) * 64, wn = (w & 1) * 64;
  int srow = lane >> 3;
  int colsw = ((lane & 7) * 8) ^ ((srow & 7) * 8);  // pre-swizzled source col
  const float SC = 0.125f * 1.44269504088896340736f;

  const u16* pA[4];
  const u16* pB[4];
  int dls[4];
#pragma unroll
  for (int j = 0; j < 4; ++j) {
    int issue = w * 4 + j;
    int row = issue * 8 + srow;
    pA[j] = A + (size_t)(m0 + row) * Kdim + colsw;
    pB[j] = Bt + (size_t)(n0 + row) * Kdim + colsw;
    dls[j] = issue * 512;
  }
  int kx = (l15 & 7) << 4;
  int ofs0 = (lg * 16) ^ kx, ofs1 = (64 + lg * 16) ^ kx;
  int rbA = (wm + l15) * 128, rbB = (wn + l15) * 128;

  f32x4 acc[4][4] = {};
  for (int kt = 0; kt < Kdim; kt += 64) {
#pragma unroll
    for (int j = 0; j < 4; ++j) {
      gload16(pA[j], Alds + dls[j]);
      gload16(pB[j], Blds + dls[j]);
      pA[j] += 64; pB[j] += 64;
    }
    __syncthreads();  // drain vmcnt -> buf ready
    __builtin_amdgcn_s_setprio(1);
#pragma unroll
    for (int kk = 0; kk < 2; ++kk) {
      int o_ = kk ? ofs1 : ofs0;
      short8 a[4], b[4];
#pragma unroll
      for (int mt = 0; mt < 4; ++mt)
        a[mt] = *(const short8*)((const char*)Alds + (rbA + o_) + mt * 2048);
#pragma unroll
      for (int nt = 0; nt < 4; ++nt)
        b[nt] = *(const short8*)((const char*)Blds + (rbB + o_) + nt * 2048);
#pragma unroll
      for (int mt = 0; mt < 4; ++mt)
#pragma unroll
        for (int nt = 0; nt < 4; ++nt)
          acc[mt][nt] = __builtin_amdgcn_mfma_f32_16x16x32_bf16(a[mt], b[nt],
                                                                acc[mt][nt], 0, 0, 0);
    }
    __builtin_amdgcn_s_setprio(0);
    __syncthreads();  // all waves done reading before next stage
  }
#pragma unroll
  for (int nt = 0; nt < 4; ++nt) {
    int n = n0 + wn + nt * 16 + l15;
    int wi = n >> 10, nn = n & 1023, h = nn >> 6, d = nn & 63;
    const float* bb = (wi == 0) ? bq : (wi == 1) ? bk : bv;
    float bval = bb[nn];
    if (wi == 2) {  // V: write transposed [B,H,D,T], 4 consecutive t -> uint2
#pragma unroll
      for (int mt = 0; mt < 4; ++mt) {
        int m = m0 + wm + mt * 16 + lg * 4;
        int mb = m >> 11, t = m & 2047;
        unsigned lo = cvtpk(acc[mt][nt][0] + bval, acc[mt][nt][1] + bval);
        unsigned hi = cvtpk(acc[mt][nt][2] + bval, acc[mt][nt][3] + bval);
        *(uint2*)&vd[((size_t)(mb * 16 + h) * 64 + d) * 2048 + t] =
            make_uint2(lo, hi);
      }
    } else if (wi == 0) {  // Q: pre-scaled by SC (softmax shift-invariance)
#pragma unroll
      for (int mt = 0; mt < 4; ++mt) {
#pragma unroll
        for (int i = 0; i < 4; ++i) {
          int m = m0 + wm + mt * 16 + lg * 4 + i;
          int mb = m >> 11, t = m & 2047;
          qd[((size_t)(mb * 16 + h) * 2048 + t) * 64 + d] =
              f2bf((acc[mt][nt][i] + bval) * SC);
        }
      }
    } else {
#pragma unroll
      for (int mt = 0; mt < 4; ++mt) {
#pragma unroll
        for (int i = 0; i < 4; ++i) {
          int m = m0 + wm + mt * 16 + lg * 4 + i;
          int mb = m >> 11, t = m & 2047;
          kd[((size_t)(mb * 16 + h) * 2048 + t) * 64 + d] =
              f2bf(acc[mt][nt][i] + bval);
        }
      }
    }
  }
}

// ---------------- proj 128x64 MFMA GEMM, BK=64, double-buffered ----------------
__global__ __launch_bounds__(256, 2) void gemm_proj_kernel(
    const u16* __restrict__ A, const u16* __restrict__ Bt,
    float* __restrict__ outf, const float* __restrict__ bias1) {
  __shared__ u16 Alds[2 * 8192];   // [2][128][64]
  __shared__ u16 Blds[2 * 4096];   // [2][64][64]
  int tid = threadIdx.x;
  int lane = tid & 63, w = tid >> 6;
  int l15 = lane & 15, lg = lane >> 4;
  int flat = blockIdx.x;
  int xcd = flat & 7, idx = flat >> 3;           // idx 0..63
  int rm = (xcd >> 1) * 8, rn = (xcd & 1) * 8;   // region: 8 mtiles x 8 ntiles
  int m0 = (rm + (idx & 7)) * 128, n0 = (rn + (idx >> 3)) * 64;
  int wm = (w >> 1) * 64, wn = (w & 1) * 32;
  int srow = lane >> 3;
  int colsw = ((lane & 7) * 8) ^ ((srow & 7) * 8);  // pre-swizzled source col

  const u16* pA[4];
  int dlsA[4];
#pragma unroll
  for (int j = 0; j < 4; ++j) {
    int issue = w * 4 + j;
    int row = issue * 8 + srow;
    pA[j] = A + (size_t)(m0 + row) * 1024 + colsw;
    dlsA[j] = issue * 512;
  }
  const u16* pB[2];
  int dlsB[2];
#pragma unroll
  for (int it = 0; it < 2; ++it) {
    int chunk = it * 256 + tid;
    int row = chunk >> 3;
    int col = ((chunk & 7) * 8) ^ ((row & 7) * 8);
    pB[it] = Bt + (size_t)(n0 + row) * 1024 + col;
    dlsB[it] = (it * 256 + w * 64) * 8;
  }
  int kx = (l15 & 7) << 4;
  int ofs0 = (lg * 16) ^ kx, ofs1 = (64 + lg * 16) ^ kx;
  int rbA = (wm + l15) * 128, rbB = (wn + l15) * 128;

  auto stage = [&](int buf) {
    u16* Ad = Alds + buf * 8192;
    u16* Bd = Blds + buf * 4096;
#pragma unroll
    for (int j = 0; j < 4; ++j) { gload16(pA[j], Ad + dlsA[j]); pA[j] += 64; }
#pragma unroll
    for (int it = 0; it < 2; ++it) { gload16(pB[it], Bd + dlsB[it]); pB[it] += 64; }
  };

  f32x4 acc[4][2] = {};
  stage(0);
  int cur = 0;
  for (int kt = 0; kt < 1024; kt += 64) {
    __syncthreads();  // drain vmcnt -> buf[cur] ready
    if (kt + 64 < 1024) stage(cur ^ 1);
    const char* Al = (const char*)Alds + cur * 16384;
    const char* Bl = (const char*)Blds + cur * 8192;
    __builtin_amdgcn_s_setprio(1);
#pragma unroll
    for (int kk = 0; kk < 2; ++kk) {
      int o_ = kk ? ofs1 : ofs0;
      short8 a[4], b[2];
#pragma unroll
      for (int mt = 0; mt < 4; ++mt)
        a[mt] = *(const short8*)(Al + (rbA + o_) + mt * 2048);
#pragma unroll
      for (int nt = 0; nt < 2; ++nt)
        b[nt] = *(const short8*)(Bl + (rbB + o_) + nt * 2048);
#pragma unroll
      for (int mt = 0; mt < 4; ++mt)
#pragma unroll
        for (int nt = 0; nt < 2; ++nt)
          acc[mt][nt] = __builtin_amdgcn_mfma_f32_16x16x32_bf16(a[mt], b[nt],
                                                                acc[mt][nt], 0, 0, 0);
    }
    __builtin_amdgcn_s_setprio(0);
    cur ^= 1;
  }
#pragma unroll
  for (int nt = 0; nt < 2; ++nt) {
    int n = n0 + wn + nt * 16 + l15;
    float bval = bias1[n];
#pragma unroll
    for (int mt = 0; mt < 4; ++mt) {
#pragma unroll
      for (int i = 0; i < 4; ++i) {
        int m = m0 + wm + mt * 16 + lg * 4 + i;
        outf[(size_t)m * 1024 + n] = acc[mt][nt][i] + bval;
      }
    }
  }
}

// ---------------- causal flash attention: shift-free + dbuf + builtin exp2 ----
// R20 structure (best). exp via __builtin_amdgcn_exp2f: same v_exp_f32 but
// scheduler-visible (no per-call s_nop, free interleave with cvtpk/adds).
// Final normalize via v_rcp (approx rcp error << bf16 output quantum).
__global__ __launch_bounds__(256, 4) void fattn_kernel(const u16* __restrict__ qb,
                                                       const u16* __restrict__ kb,
                                                       const u16* __restrict__ vt,
                                                       u16* __restrict__ y) {
  __shared__ u16 Klds[2 * 4096];
  __shared__ u16 Vlds[2 * 4096];   // V^T: [d][kv], swizzled
  __shared__ u16 Plds[4 * 1024];
  int tid = threadIdx.x, lane = tid & 63, w = tid >> 6;
  int l15 = lane & 15, lg = lane >> 4;
  int flat = blockIdx.x;
  int bh = flat & 31;
  int g = flat >> 5;                  // dispatch round group 0..31
  int qt;
  switch (g >> 3) {                   // complementary rounds: 31..24,0..7,23..16,8..15
    case 0:  qt = 31 - g; break;
    case 1:  qt = g - 8;  break;
    case 2:  qt = 39 - g; break;
    default: qt = g - 16; break;
  }
  size_t base = (size_t)bh * 2048 * 64;
  int mb = bh >> 4, h = bh & 15;

  // ---- hoisted staging geometry (advance per tile: K +4096, V +64 elem) ----
  int r0 = tid >> 3, c0 = ((tid & 7) * 8) ^ ((r0 & 7) << 3);
  int r1 = (256 + tid) >> 3, c1 = ((tid & 7) * 8) ^ ((r1 & 7) << 3);
  const u16* pK0 = kb + base + (size_t)r0 * 64 + c0;
  const u16* pK1 = kb + base + (size_t)r1 * 64 + c1;
  const u16* pV0 = vt + base + (size_t)r0 * 2048 + c0;
  const u16* pV1 = vt + base + (size_t)r1 * 2048 + c1;
  int dk0 = w * 512, dk1 = (256 + w * 64) * 8;   // LDS dest offsets (u16)
  // ---- hoisted LDS read bases (bytes); shared by K, V, P reads ----
  int kx = (l15 & 7) << 4;
  int rb0 = l15 * 128 + ((lg * 16) ^ kx);
  int rb1 = l15 * 128 + ((64 + lg * 16) ^ kx);
  char* pbase = (char*)Plds + w * 2048;
  int pw0 = l15 * 128 + ((lg * 8) ^ kx);
  int pw1 = l15 * 128 + ((32 + lg * 8) ^ kx);
  int pw2 = l15 * 128 + ((64 + lg * 8) ^ kx);
  int pw3 = l15 * 128 + ((96 + lg * 8) ^ kx);

  int qw = qt * 64 + w * 16;
  int qr = qw + l15;
  short8 qf[2];
#pragma unroll
  for (int kk = 0; kk < 2; ++kk)
    qf[kk] = *(const short8*)&qb[base + (size_t)qr * 64 + kk * 32 + lg * 8];
  f32x4 o[4] = {};
  float lrow = 0.f;
  {  // prologue stage tile 0 into buf 0
    gload16(pK0, Klds + dk0); gload16(pK1, Klds + dk1);
    gload16(pV0, Vlds + dk0); gload16(pV1, Vlds + dk1);
    pK0 += 4096; pK1 += 4096; pV0 += 64; pV1 += 64;
  }
  int cb = 0;
  int ntiles = qt + 1;
  for (int j = 0; j < ntiles; ++j) {
    __syncthreads();  // drains vmcnt: buf[cb] ready; prev reads of cb^1 done
    if (j + 1 < ntiles) {  // prefetch next tile into cb^1 (returns under compute)
      u16* kd_ = Klds + (cb ^ 1) * 4096;
      u16* vd_ = Vlds + (cb ^ 1) * 4096;
      gload16(pK0, kd_ + dk0); gload16(pK1, kd_ + dk1);
      gload16(pV0, vd_ + dk0); gload16(pV1, vd_ + dk1);
      pK0 += 4096; pK1 += 4096; pV0 += 64; pV1 += 64;
    }
    const char* kl = (const char*)Klds + cb * 8192;
    const char* vl = (const char*)Vlds + cb * 8192;
    // S^T = K Q^T  (swapped operands; Q pre-scaled by 0.125*log2e)
    f32x4 s[4] = {};
    __builtin_amdgcn_s_setprio(1);
#pragma unroll
    for (int kk = 0; kk < 2; ++kk) {
      int o_ = kk ? rb1 : rb0;
      short8 ka[4];
#pragma unroll
      for (int nt = 0; nt < 4; ++nt)
        ka[nt] = *(const short8*)(kl + o_ + nt * 2048);
#pragma unroll
      for (int nt = 0; nt < 4; ++nt)
        s[nt] = __builtin_amdgcn_mfma_f32_16x16x32_bf16(ka[nt], qf[kk], s[nt], 0, 0, 0);
    }
    __builtin_amdgcn_s_setprio(0);
    // p = 2^s via v_exp_f32 (shift-free); masked entries -> 0
    float p[16];
    if (j == qt) {
      int k0 = j * 64;
#pragma unroll
      for (int nt = 0; nt < 4; ++nt)
#pragma unroll
        for (int i = 0; i < 4; ++i) {
          int ka_ = k0 + nt * 16 + lg * 4 + i;
          p[nt * 4 + i] = (ka_ > qr) ? 0.f : __builtin_amdgcn_exp2f(s[nt][i]);
        }
    } else {
#pragma unroll
      for (int nt = 0; nt < 4; ++nt)
#pragma unroll
        for (int i = 0; i < 4; ++i) p[nt * 4 + i] = __builtin_amdgcn_exp2f(s[nt][i]);
    }
    // P[q][k] -> LDS first (ds latency overlaps the lrow adds below)
    *(uint2*)(pbase + pw0) = make_uint2(cvtpk(p[0], p[1]), cvtpk(p[2], p[3]));
    *(uint2*)(pbase + pw1) = make_uint2(cvtpk(p[4], p[5]), cvtpk(p[6], p[7]));
    *(uint2*)(pbase + pw2) = make_uint2(cvtpk(p[8], p[9]), cvtpk(p[10], p[11]));
    *(uint2*)(pbase + pw3) = make_uint2(cvtpk(p[12], p[13]), cvtpk(p[14], p[15]));
    float pr0 = ((p[0] + p[1]) + (p[2] + p[3])) + ((p[4] + p[5]) + (p[6] + p[7]));
    float pr1 = ((p[8] + p[9]) + (p[10] + p[11])) + ((p[12] + p[13]) + (p[14] + p[15]));
    lrow += pr0 + pr1;  // per-lane partial; reduced after the loop
    // O^T += V^T P^T  (swapped operands)
    __builtin_amdgcn_s_setprio(1);
#pragma unroll
    for (int kk = 0; kk < 2; ++kk) {
      int o_ = kk ? rb1 : rb0;
      short8 ap = *(const short8*)(pbase + o_);
#pragma unroll
      for (int dn = 0; dn < 4; ++dn) {
        short8 bv_ = *(const short8*)(vl + o_ + dn * 2048);
        o[dn] = __builtin_amdgcn_mfma_f32_16x16x32_bf16(bv_, ap, o[dn], 0, 0, 0);
      }
    }
    __builtin_amdgcn_s_setprio(0);
    cb ^= 1;
  }
  // combine lrow partials across the 4 lane-groups of each q-row
  lrow += __shfl_xor(lrow, 16);
  lrow += __shfl_xor(lrow, 32);
  float inv = __builtin_amdgcn_rcpf(lrow);
  size_t rb = ((size_t)(mb * 2048 + qr)) * 1024 + (size_t)h * 64;
#pragma unroll
  for (int dn = 0; dn < 4; ++dn) {
    unsigned lo = cvtpk(o[dn][0] * inv, o[dn][1] * inv);
    unsigned hi = cvtpk(o[dn][2] * inv, o[dn][3] * inv);
    *(uint2*)&y[rb + dn * 16 + lg * 4] = make_uint2(lo, hi);
  }
}

extern "C" void kernel_launch(void* const* d_in, const int* in_sizes, int n_in,
                              void* d_out, int out_size, void* d_ws, size_t ws_size,
                              hipStream_t stream) {
  const float* x  = (const float*)d_in[0];
  const float* Wq = (const float*)d_in[1];
  const float* bq = (const float*)d_in[2];
  const float* Wk = (const float*)d_in[3];
  const float* bk = (const float*)d_in[4];
  const float* Wv = (const float*)d_in[5];
  const float* bv = (const float*)d_in[6];
  const float* Wp = (const float*)d_in[7];
  const float* bp = (const float*)d_in[8];
  float* out = (float*)d_out;
  char* ws = (char*)d_ws;
  u16* xb   = (u16*)(ws);
  u16* wt   = (u16*)(ws + ((size_t)8 << 20));
  u16* qbuf = (u16*)(ws + ((size_t)16 << 20));
  u16* kbuf = (u16*)(ws + ((size_t)24 << 20));
  u16* vtb  = (u16*)(ws + ((size_t)32 << 20));  // V^T written by QKV epilogue
  u16* ybuf = (u16*)(ws + ((size_t)40 << 20));

  prep_kernel<<<dim3(3072), dim3(256), 0, stream>>>(x, Wq, Wk, Wv, Wp, xb, wt);
  // QKV: M=4096 (GM=32), N=3072 (GN=24); per-XCD region 8x12; single-buffered
  gemm_qkv_kernel<<<dim3(768), dim3(256), 0, stream>>>(
      xb, wt, 1024, 32, 24, 8, 12, qbuf, kbuf, vtb, bq, bk, bv);
  fattn_kernel<<<dim3(1024), dim3(256), 0, stream>>>(qbuf, kbuf, vtb, ybuf);
  // proj: 128x64 tiles, grid 512 (2 blocks/CU co-resident), double-buffered
  gemm_proj_kernel<<<dim3(512), dim3(256), 0, stream>>>(
      ybuf, wt + (size_t)3 * 1024 * 1024, out, bp);
  (void)in_sizes; (void)n_in; (void)out_size; (void)ws_size;
}

// Round 22
// 91.636 us; speedup vs baseline: 1.2215x; 1.0190x over previous
//
#include <hip/hip_runtime.h>
#include <hip/hip_bf16.h>
#include <stdint.h>

typedef unsigned short u16;
typedef __attribute__((ext_vector_type(8))) short short8;
typedef __attribute__((ext_vector_type(4))) float f32x4;

// ws layout (bytes): [0,8M) x_bf16 [8M,16M) Wt(4x1Mx2B) [16M,24M) q
// [24M,32M) k [32M,40M) v^T [B,H,D,T] [40M,48M) y
static __device__ __forceinline__ u16 f2bf(float f) {
  unsigned u = __builtin_bit_cast(unsigned, f);
  u += 0x7fffu + ((u >> 16) & 1u);
  return (u16)(u >> 16);
}

static __device__ __forceinline__ unsigned cvtpk(float lo, float hi) {
  unsigned r;
  asm("v_cvt_pk_bf16_f32 %0, %1, %2" : "=v"(r) : "v"(lo), "v"(hi));
  return r;
}

static __device__ __forceinline__ void gload16(const u16* g, u16* l) {
  __builtin_amdgcn_global_load_lds(
      (__attribute__((address_space(1))) void*)const_cast<u16*>(g),
      (__attribute__((address_space(3))) void*)l, 16, 0, 0);
}

// ---------------- fused prep: x fp32->bf16 (blocks 0..2047) +
//                  W [k][n] fp32 -> Wt [n][k] bf16 (blocks 2048..3071) ----------
__global__ __launch_bounds__(256) void prep_kernel(
    const float* __restrict__ x, const float* __restrict__ Wq,
    const float* __restrict__ Wk, const float* __restrict__ Wv,
    const float* __restrict__ Wp, u16* __restrict__ xb, u16* __restrict__ wt) {
  __shared__ float tile[64][65];
  int b = blockIdx.x;
  if (b < 2048) {
    size_t i = (size_t)b * 256 + threadIdx.x;  // 8 floats per thread
    const float4* xp = (const float4*)x + i * 2;
    float4 a = xp[0], v = xp[1];
    union { u16 u[8]; int4 q; } r;
    r.u[0] = f2bf(a.x); r.u[1] = f2bf(a.y); r.u[2] = f2bf(a.z); r.u[3] = f2bf(a.w);
    r.u[4] = f2bf(v.x); r.u[5] = f2bf(v.y); r.u[6] = f2bf(v.z); r.u[7] = f2bf(v.w);
    *(int4*)(xb + i * 8) = r.q;
  } else {
    int wb = b - 2048;
    int wz = wb >> 8, r8 = wb & 255;
    const float* W = (wz == 0) ? Wq : (wz == 1) ? Wk : (wz == 2) ? Wv : Wp;
    int n0 = (r8 & 15) * 64, k0 = (r8 >> 4) * 64;
    int tx = threadIdx.x & 63, ty = threadIdx.x >> 6;
#pragma unroll
    for (int r = 0; r < 16; ++r)
      tile[ty + 4 * r][tx] = W[(size_t)(k0 + ty + 4 * r) * 1024 + n0 + tx];
    __syncthreads();
    u16* dst = wt + (size_t)wz * 1024 * 1024;
#pragma unroll
    for (int r = 0; r < 16; ++r) {
      int n = ty + 4 * r;
      dst[(size_t)(n0 + n) * 1024 + k0 + tx] = f2bf(tile[tx][n]);
    }
  }
}

// ---------------- QKV 128x128 MFMA GEMM, BK=64, single-buffered ----------------
// Q pre-scaled by 0.125*log2(e). NEW: wave-local LDS-bounce epilogue -- each
// wave's 64x64 tile covers one (wi,h,mb) and full d 0..63, so after a
// transpose bounce every global store is a coalesced 1KB burst (8 int4/lane
// replaces 48 scattered u16 + 16 strided uint2; kills the 1.7x write amp).
__global__ __launch_bounds__(256, 2) void gemm_qkv_kernel(
    const u16* __restrict__ A, const u16* __restrict__ Bt, int Kdim,
    int GM, int GN, int RM, int RN,
    u16* __restrict__ qd, u16* __restrict__ kd, u16* __restrict__ vd,
    const float* __restrict__ bq, const float* __restrict__ bk,
    const float* __restrict__ bv) {
  __shared__ u16 lds[16384];   // [0,8192) A-tile, [8192,16384) B-tile; reused
  int tid = threadIdx.x;
  int lane = tid & 63, w = tid >> 6;
  int l15 = lane & 15, lg = lane >> 4;
  int flat = blockIdx.x;
  int xcd = flat & 7, idx = flat >> 3;
  int rnc = GN / RN;
  int rm = (xcd / rnc) * RM, rn = (xcd % rnc) * RN;
  int im = idx % RM, in_ = idx / RM;
  int m0 = (rm + im) * 128, n0 = (rn + in_) * 128;
  int wm = (w >> 1) * 64, wn = (w & 1) * 64;
  int srow = lane >> 3;
  int colsw = ((lane & 7) * 8) ^ ((srow & 7) * 8);  // pre-swizzled source col
  const float SC = 0.125f * 1.44269504088896340736f;

  const u16* pA[4];
  const u16* pB[4];
  int dls[4];
#pragma unroll
  for (int j = 0; j < 4; ++j) {
    int issue = w * 4 + j;
    int row = issue * 8 + srow;
    pA[j] = A + (size_t)(m0 + row) * Kdim + colsw;
    pB[j] = Bt + (size_t)(n0 + row) * Kdim + colsw;
    dls[j] = issue * 512;
  }
  int kx = (l15 & 7) << 4;
  int ofs0 = (lg * 16) ^ kx, ofs1 = (64 + lg * 16) ^ kx;
  int rbA = (wm + l15) * 128, rbB = (wn + l15) * 128;

  f32x4 acc[4][4] = {};
  for (int kt = 0; kt < Kdim; kt += 64) {
#pragma unroll
    for (int j = 0; j < 4; ++j) {
      gload16(pA[j], lds + dls[j]);
      gload16(pB[j], lds + 8192 + dls[j]);
      pA[j] += 64; pB[j] += 64;
    }
    __syncthreads();  // drain vmcnt -> buf ready
    __builtin_amdgcn_s_setprio(1);
#pragma unroll
    for (int kk = 0; kk < 2; ++kk) {
      int o_ = kk ? ofs1 : ofs0;
      short8 a[4], b[4];
#pragma unroll
      for (int mt = 0; mt < 4; ++mt)
        a[mt] = *(const short8*)((const char*)lds + (rbA + o_) + mt * 2048);
#pragma unroll
      for (int nt = 0; nt < 4; ++nt)
        b[nt] = *(const short8*)((const char*)lds + 16384 + (rbB + o_) + nt * 2048);
#pragma unroll
      for (int mt = 0; mt < 4; ++mt)
#pragma unroll
        for (int nt = 0; nt < 4; ++nt)
          acc[mt][nt] = __builtin_amdgcn_mfma_f32_16x16x32_bf16(a[mt], b[nt],
                                                                acc[mt][nt], 0, 0, 0);
    }
    __builtin_amdgcn_s_setprio(0);
    __syncthreads();  // all waves done reading before next stage
  }
  // ---- wave-local LDS-bounce epilogue (post-loop barrier already passed) ----
  int n_base = n0 + wn;                      // 64-aligned
  int wi = n_base >> 10, h = (n_base >> 6) & 15;
  int m_base = m0 + wm;
  int mb2 = m_base >> 11, t0 = m_base & 2047;
  const float* bb = (wi == 0) ? bq : (wi == 1) ? bk : bv;
  u16* lw = lds + w * 4096;                  // 8KB per wave, wave-local
  int nb10 = n_base & 1023;
  if (wi == 2) {  // V: LDS as [d][t_local] (4 consecutive t pack to uint2)
#pragma unroll
    for (int nt = 0; nt < 4; ++nt) {
      int d = nt * 16 + l15;
      float bval = bb[nb10 + d];
#pragma unroll
      for (int mt = 0; mt < 4; ++mt) {
        int tl = mt * 16 + lg * 4;
        unsigned lo = cvtpk(acc[mt][nt][0] + bval, acc[mt][nt][1] + bval);
        unsigned hi2 = cvtpk(acc[mt][nt][2] + bval, acc[mt][nt][3] + bval);
        *(uint2*)&lw[d * 64 + (tl ^ ((d & 7) * 8))] = make_uint2(lo, hi2);
      }
    }
  } else {        // Q/K: LDS as [t_local][d]
    float scl = (wi == 0) ? SC : 1.f;
#pragma unroll
    for (int nt = 0; nt < 4; ++nt) {
      int d = nt * 16 + l15;
      float bval = bb[nb10 + d];
#pragma unroll
      for (int mt = 0; mt < 4; ++mt)
#pragma unroll
        for (int i = 0; i < 4; ++i) {
          int tl = mt * 16 + lg * 4 + i;
          lw[tl * 64 + (d ^ ((tl & 7) * 8))] = f2bf((acc[mt][nt][i] + bval) * scl);
        }
    }
  }
  // coalesced store: 8 rows/instr, 1KB bursts (lgkm ordering is wave-local)
  int row0 = lane >> 3, off16 = (lane & 7) * 8;
  if (wi == 2) {
    size_t gb = ((size_t)(mb2 * 16 + h) * 64) * 2048 + t0;
#pragma unroll
    for (int c = 0; c < 8; ++c) {
      int row = c * 8 + row0;   // d
      int4 v = *(const int4*)&lw[row * 64 + (off16 ^ ((row & 7) * 8))];
      *(int4*)&vd[gb + (size_t)row * 2048 + off16] = v;
    }
  } else {
    u16* dst = (wi == 0) ? qd : kd;
    size_t gb = ((size_t)(mb2 * 16 + h) * 2048 + t0) * 64;
#pragma unroll
    for (int c = 0; c < 8; ++c) {
      int row = c * 8 + row0;   // t_local
      int4 v = *(const int4*)&lw[row * 64 + (off16 ^ ((row & 7) * 8))];
      *(int4*)&dst[gb + (size_t)row * 64 + off16] = v;
    }
  }
}

// ---------------- proj 128x64 MFMA GEMM, BK=64, double-buffered ----------------
__global__ __launch_bounds__(256, 2) void gemm_proj_kernel(
    const u16* __restrict__ A, const u16* __restrict__ Bt,
    float* __restrict__ outf, const float* __restrict__ bias1) {
  __shared__ u16 Alds[2 * 8192];   // [2][128][64]
  __shared__ u16 Blds[2 * 4096];   // [2][64][64]
  int tid = threadIdx.x;
  int lane = tid & 63, w = tid >> 6;
  int l15 = lane & 15, lg = lane >> 4;
  int flat = blockIdx.x;
  int xcd = flat & 7, idx = flat >> 3;           // idx 0..63
  int rm = (xcd >> 1) * 8, rn = (xcd & 1) * 8;   // region: 8 mtiles x 8 ntiles
  int m0 = (rm + (idx & 7)) * 128, n0 = (rn + (idx >> 3)) * 64;
  int wm = (w >> 1) * 64, wn = (w & 1) * 32;
  int srow = lane >> 3;
  int colsw = ((lane & 7) * 8) ^ ((srow & 7) * 8);  // pre-swizzled source col

  const u16* pA[4];
  int dlsA[4];
#pragma unroll
  for (int j = 0; j < 4; ++j) {
    int issue = w * 4 + j;
    int row = issue * 8 + srow;
    pA[j] = A + (size_t)(m0 + row) * 1024 + colsw;
    dlsA[j] = issue * 512;
  }
  const u16* pB[2];
  int dlsB[2];
#pragma unroll
  for (int it = 0; it < 2; ++it) {
    int chunk = it * 256 + tid;
    int row = chunk >> 3;
    int col = ((chunk & 7) * 8) ^ ((row & 7) * 8);
    pB[it] = Bt + (size_t)(n0 + row) * 1024 + col;
    dlsB[it] = (it * 256 + w * 64) * 8;
  }
  int kx = (l15 & 7) << 4;
  int ofs0 = (lg * 16) ^ kx, ofs1 = (64 + lg * 16) ^ kx;
  int rbA = (wm + l15) * 128, rbB = (wn + l15) * 128;

  auto stage = [&](int buf) {
    u16* Ad = Alds + buf * 8192;
    u16* Bd = Blds + buf * 4096;
#pragma unroll
    for (int j = 0; j < 4; ++j) { gload16(pA[j], Ad + dlsA[j]); pA[j] += 64; }
#pragma unroll
    for (int it = 0; it < 2; ++it) { gload16(pB[it], Bd + dlsB[it]); pB[it] += 64; }
  };

  f32x4 acc[4][2] = {};
  stage(0);
  int cur = 0;
  for (int kt = 0; kt < 1024; kt += 64) {
    __syncthreads();  // drain vmcnt -> buf[cur] ready
    if (kt + 64 < 1024) stage(cur ^ 1);
    const char* Al = (const char*)Alds + cur * 16384;
    const char* Bl = (const char*)Blds + cur * 8192;
    __builtin_amdgcn_s_setprio(1);
#pragma unroll
    for (int kk = 0; kk < 2; ++kk) {
      int o_ = kk ? ofs1 : ofs0;
      short8 a[4], b[2];
#pragma unroll
      for (int mt = 0; mt < 4; ++mt)
        a[mt] = *(const short8*)(Al + (rbA + o_) + mt * 2048);
#pragma unroll
      for (int nt = 0; nt < 2; ++nt)
        b[nt] = *(const short8*)(Bl + (rbB + o_) + nt * 2048);
#pragma unroll
      for (int mt = 0; mt < 4; ++mt)
#pragma unroll
        for (int nt = 0; nt < 2; ++nt)
          acc[mt][nt] = __builtin_amdgcn_mfma_f32_16x16x32_bf16(a[mt], b[nt],
                                                                acc[mt][nt], 0, 0, 0);
    }
    __builtin_amdgcn_s_setprio(0);
    cur ^= 1;
  }
#pragma unroll
  for (int nt = 0; nt < 2; ++nt) {
    int n = n0 + wn + nt * 16 + l15;
    float bval = bias1[n];
#pragma unroll
    for (int mt = 0; mt < 4; ++mt) {
#pragma unroll
      for (int i = 0; i < 4; ++i) {
        int m = m0 + wm + mt * 16 + lg * 4 + i;
        outf[(size_t)m * 1024 + n] = acc[mt][nt][i] + bval;
      }
    }
  }
}

// ---------------- causal flash attention: shift-free + dbuf + builtin exp2 ----
// (R21 version, best.)
__global__ __launch_bounds__(256, 4) void fattn_kernel(const u16* __restrict__ qb,
                                                       const u16* __restrict__ kb,
                                                       const u16* __restrict__ vt,
                                                       u16* __restrict__ y) {
  __shared__ u16 Klds[2 * 4096];
  __shared__ u16 Vlds[2 * 4096];   // V^T: [d][kv], swizzled
  __shared__ u16 Plds[4 * 1024];
  int tid = threadIdx.x, lane = tid & 63, w = tid >> 6;
  int l15 = lane & 15, lg = lane >> 4;
  int flat = blockIdx.x;
  int bh = flat & 31;
  int g = flat >> 5;                  // dispatch round group 0..31
  int qt;
  switch (g >> 3) {                   // complementary rounds: 31..24,0..7,23..16,8..15
    case 0:  qt = 31 - g; break;
    case 1:  qt = g - 8;  break;
    case 2:  qt = 39 - g; break;
    default: qt = g - 16; break;
  }
  size_t base = (size_t)bh * 2048 * 64;
  int mb = bh >> 4, h = bh & 15;

  // ---- hoisted staging geometry (advance per tile: K +4096, V +64 elem) ----
  int r0 = tid >> 3, c0 = ((tid & 7) * 8) ^ ((r0 & 7) << 3);
  int r1 = (256 + tid) >> 3, c1 = ((tid & 7) * 8) ^ ((r1 & 7) << 3);
  const u16* pK0 = kb + base + (size_t)r0 * 64 + c0;
  const u16* pK1 = kb + base + (size_t)r1 * 64 + c1;
  const u16* pV0 = vt + base + (size_t)r0 * 2048 + c0;
  const u16* pV1 = vt + base + (size_t)r1 * 2048 + c1;
  int dk0 = w * 512, dk1 = (256 + w * 64) * 8;   // LDS dest offsets (u16)
  // ---- hoisted LDS read bases (bytes); shared by K, V, P reads ----
  int kx = (l15 & 7) << 4;
  int rb0 = l15 * 128 + ((lg * 16) ^ kx);
  int rb1 = l15 * 128 + ((64 + lg * 16) ^ kx);
  char* pbase = (char*)Plds + w * 2048;
  int pw0 = l15 * 128 + ((lg * 8) ^ kx);
  int pw1 = l15 * 128 + ((32 + lg * 8) ^ kx);
  int pw2 = l15 * 128 + ((64 + lg * 8) ^ kx);
  int pw3 = l15 * 128 + ((96 + lg * 8) ^ kx);

  int qw = qt * 64 + w * 16;
  int qr = qw + l15;
  short8 qf[2];
#pragma unroll
  for (int kk = 0; kk < 2; ++kk)
    qf[kk] = *(const short8*)&qb[base + (size_t)qr * 64 + kk * 32 + lg * 8];
  f32x4 o[4] = {};
  float lrow = 0.f;
  {  // prologue stage tile 0 into buf 0
    gload16(pK0, Klds + dk0); gload16(pK1, Klds + dk1);
    gload16(pV0, Vlds + dk0); gload16(pV1, Vlds + dk1);
    pK0 += 4096; pK1 += 4096; pV0 += 64; pV1 += 64;
  }
  int cb = 0;
  int ntiles = qt + 1;
  for (int j = 0; j < ntiles; ++j) {
    __syncthreads();  // drains vmcnt: buf[cb] ready; prev reads of cb^1 done
    if (j + 1 < ntiles) {  // prefetch next tile into cb^1 (returns under compute)
      u16* kd_ = Klds + (cb ^ 1) * 4096;
      u16* vd_ = Vlds + (cb ^ 1) * 4096;
      gload16(pK0, kd_ + dk0); gload16(pK1, kd_ + dk1);
      gload16(pV0, vd_ + dk0); gload16(pV1, vd_ + dk1);
      pK0 += 4096; pK1 += 4096; pV0 += 64; pV1 += 64;
    }
    const char* kl = (const char*)Klds + cb * 8192;
    const char* vl = (const char*)Vlds + cb * 8192;
    // S^T = K Q^T  (swapped operands; Q pre-scaled by 0.125*log2e)
    f32x4 s[4] = {};
    __builtin_amdgcn_s_setprio(1);
#pragma unroll
    for (int kk = 0; kk < 2; ++kk) {
      int o_ = kk ? rb1 : rb0;
      short8 ka[4];
#pragma unroll
      for (int nt = 0; nt < 4; ++nt)
        ka[nt] = *(const short8*)(kl + o_ + nt * 2048);
#pragma unroll
      for (int nt = 0; nt < 4; ++nt)
        s[nt] = __builtin_amdgcn_mfma_f32_16x16x32_bf16(ka[nt], qf[kk], s[nt], 0, 0, 0);
    }
    __builtin_amdgcn_s_setprio(0);
    // p = 2^s via v_exp_f32 (shift-free); masked entries -> 0
    float p[16];
    if (j == qt) {
      int k0 = j * 64;
#pragma unroll
      for (int nt = 0; nt < 4; ++nt)
#pragma unroll
        for (int i = 0; i < 4; ++i) {
          int ka_ = k0 + nt * 16 + lg * 4 + i;
          p[nt * 4 + i] = (ka_ > qr) ? 0.f : __builtin_amdgcn_exp2f(s[nt][i]);
        }
    } else {
#pragma unroll
      for (int nt = 0; nt < 4; ++nt)
#pragma unroll
        for (int i = 0; i < 4; ++i) p[nt * 4 + i] = __builtin_amdgcn_exp2f(s[nt][i]);
    }
    // P[q][k] -> LDS first (ds latency overlaps the lrow adds below)
    *(uint2*)(pbase + pw0) = make_uint2(cvtpk(p[0], p[1]), cvtpk(p[2], p[3]));
    *(uint2*)(pbase + pw1) = make_uint2(cvtpk(p[4], p[5]), cvtpk(p[6], p[7]));
    *(uint2*)(pbase + pw2) = make_uint2(cvtpk(p[8], p[9]), cvtpk(p[10], p[11]));
    *(uint2*)(pbase + pw3) = make_uint2(cvtpk(p[12], p[13]), cvtpk(p[14], p[15]));
    float pr0 = ((p[0] + p[1]) + (p[2] + p[3])) + ((p[4] + p[5]) + (p[6] + p[7]));
    float pr1 = ((p[8] + p[9]) + (p[10] + p[11])) + ((p[12] + p[13]) + (p[14] + p[15]));
    lrow += pr0 + pr1;  // per-lane partial; reduced after the loop
    // O^T += V^T P^T  (swapped operands)
    __builtin_amdgcn_s_setprio(1);
#pragma unroll
    for (int kk = 0; kk < 2; ++kk) {
      int o_ = kk ? rb1 : rb0;
      short8 ap = *(const short8*)(pbase + o_);
#pragma unroll
      for (int dn = 0; dn < 4; ++dn) {
        short8 bv_ = *(const short8*)(vl + o_ + dn * 2048);
        o[dn] = __builtin_amdgcn_mfma_f32_16x16x32_bf16(bv_, ap, o[dn], 0, 0, 0);
      }
    }
    __builtin_amdgcn_s_setprio(0);
    cb ^= 1;
  }
  // combine lrow partials across the 4 lane-groups of each q-row
  lrow += __shfl_xor(lrow, 16);
  lrow += __shfl_xor(lrow, 32);
  float inv = __builtin_amdgcn_rcpf(lrow);
  size_t rb = ((size_t)(mb * 2048 + qr)) * 1024 + (size_t)h * 64;
#pragma unroll
  for (int dn = 0; dn < 4; ++dn) {
    unsigned lo = cvtpk(o[dn][0] * inv, o[dn][1] * inv);
    unsigned hi = cvtpk(o[dn][2] * inv, o[dn][3] * inv);
    *(uint2*)&y[rb + dn * 16 + lg * 4] = make_uint2(lo, hi);
  }
}

extern "C" void kernel_launch(void* const* d_in, const int* in_sizes, int n_in,
                              void* d_out, int out_size, void* d_ws, size_t ws_size,
                              hipStream_t stream) {
  const float* x  = (const float*)d_in[0];
  const float* Wq = (const float*)d_in[1];
  const float* bq = (const float*)d_in[2];
  const float* Wk = (const float*)d_in[3];
  const float* bk = (const float*)d_in[4];
  const float* Wv = (const float*)d_in[5];
  const float* bv = (const float*)d_in[6];
  const float* Wp = (const float*)d_in[7];
  const float* bp = (const float*)d_in[8];
  float* out = (float*)d_out;
  char* ws = (char*)d_ws;
  u16* xb   = (u16*)(ws);
  u16* wt   = (u16*)(ws + ((size_t)8 << 20));
  u16* qbuf = (u16*)(ws + ((size_t)16 << 20));
  u16* kbuf = (u16*)(ws + ((size_t)24 << 20));
  u16* vtb  = (u16*)(ws + ((size_t)32 << 20));  // V^T written by QKV epilogue
  u16* ybuf = (u16*)(ws + ((size_t)40 << 20));

  prep_kernel<<<dim3(3072), dim3(256), 0, stream>>>(x, Wq, Wk, Wv, Wp, xb, wt);
  // QKV: M=4096 (GM=32), N=3072 (GN=24); per-XCD region 8x12; single-buffered
  gemm_qkv_kernel<<<dim3(768), dim3(256), 0, stream>>>(
      xb, wt, 1024, 32, 24, 8, 12, qbuf, kbuf, vtb, bq, bk, bv);
  fattn_kernel<<<dim3(1024), dim3(256), 0, stream>>>(qbuf, kbuf, vtb, ybuf);
  // proj: 128x64 tiles, grid 512 (2 blocks/CU co-resident), double-buffered
  gemm_proj_kernel<<<dim3(512), dim3(256), 0, stream>>>(
      ybuf, wt + (size_t)3 * 1024 * 1024, out, bp);
  (void)in_sizes; (void)n_in; (void)out_size; (void)ws_size;
}